// Round 4
// baseline (216.842 us; speedup 1.0000x reference)
//
#include <hip/hip_runtime.h>
#include <hip/hip_fp16.h>

#define N_SRC 16384
#define N_TGT 65536
#define KNN 8
#define CMV 16
#define CSKIP 2
#define SSC 32
#define HID 64
#define MVD 16

#define OUT_MV_ELEMS (N_TGT * CMV * MVD)   // 16777216 floats
#define PROJ_OFFSET 512                    // floats reserved at start of ws (skip Weff rows)
// fp16 proj table at ws + PROJ_OFFSET: N_SRC x 256 halves (512 B/row, 8 MB)

typedef float vf4 __attribute__((ext_vector_type(4)));

__device__ __forceinline__ float4 nt_load4(const float* p) {
    vf4 v = __builtin_nontemporal_load((const vf4*)p);
    return make_float4(v.x, v.y, v.z, v.w);
}
__device__ __forceinline__ void nt_store4(float* p, float4 o) {
    vf4 v; v.x = o.x; v.y = o.y; v.z = o.z; v.w = o.w;
    __builtin_nontemporal_store(v, (vf4*)p);
}

// gelu tanh-approx with native exp: tanh(y) = 1 - 2/(e^{2y}+1)  (overflow-safe)
__device__ __forceinline__ float gelu_tanh(float x) {
    const float k0 = 0.7978845608028654f;  // sqrt(2/pi)
    const float k1 = 0.044715f;
    float yy = k0 * (x + k1 * x * x * x);
    float e = __expf(2.0f * yy);
    return 0.5f * x * (2.0f - 2.0f / (e + 1.0f));
}

// ---------------------------------------------------------------------------
// Kernel A: mv_proj[s][d][i] = sum_c mv_src[s][c][i] * W_eff[c][d] (c<16), fp16.
// W_eff = W1_mv @ W2_mv (mv path fully linear).  Block 0 writes skip rows
// (c=16,17) of W_eff to ws[0..31] (f32).
// ---------------------------------------------------------------------------
__global__ __launch_bounds__(256) void kA_preproject(
        const float* __restrict__ mv_src,
        const float* __restrict__ W1_mv,
        const float* __restrict__ W2_mv,
        float* __restrict__ ws) {
    __shared__ float sWeff[CMV][MVD];
    int tid = threadIdx.x;
    {
        int c = tid >> 4, d = tid & 15;
        float a = 0.f;
        #pragma unroll 8
        for (int h = 0; h < HID; ++h)
            a = fmaf(W1_mv[c * HID + h], W2_mv[h * MVD + d], a);
        sWeff[c][d] = a;
    }
    if (blockIdx.x == 0 && tid < 32) {
        int j = tid >> 4, d = tid & 15;
        float a = 0.f;
        #pragma unroll 8
        for (int h = 0; h < HID; ++h)
            a = fmaf(W1_mv[(CMV + j) * HID + h], W2_mv[h * MVD + d], a);
        ws[j * MVD + d] = a;
    }
    __syncthreads();

    int lane = tid & 63;
    int d = lane >> 2, q = lane & 3;
    float wcol[CMV];
    #pragma unroll
    for (int c = 0; c < CMV; ++c) wcol[c] = sWeff[c][d];

    __half* proj = (__half*)(ws + PROJ_OFFSET);
    int wid = (int)((blockIdx.x * blockDim.x + tid) >> 6);
    int nw  = (int)((gridDim.x * blockDim.x) >> 6);
    for (int s = wid; s < N_SRC; s += nw) {
        const float* row = mv_src + (size_t)s * 256;
        float4 o = make_float4(0.f, 0.f, 0.f, 0.f);
        #pragma unroll
        for (int c = 0; c < CMV; ++c) {
            float4 v = *(const float4*)(row + c * 16 + q * 4);
            o.x = fmaf(v.x, wcol[c], o.x);
            o.y = fmaf(v.y, wcol[c], o.y);
            o.z = fmaf(v.z, wcol[c], o.z);
            o.w = fmaf(v.w, wcol[c], o.w);
        }
        union { __half2 h[2]; uint2 u; } P;
        P.h[0] = __floats2half2_rn(o.x, o.y);
        P.h[1] = __floats2half2_rn(o.z, o.w);
        *(uint2*)(proj + (size_t)s * 256 + lane * 4) = P.u;
    }
}

// ---------------------------------------------------------------------------
// Fused kernel: mv gather path + scalar MLP path in one kernel.
// One wave owns 8 targets.  The scalar path's gathers/GEMMs execute in the
// issue slots left idle by the mv gather latency (VALUBusy was 26%).
// Per-wave LDS X/H buffer -> no cross-wave barriers after weight staging.
// NT stores for out (72 MB one-shot) protect the 8 MB proj table in L2.
// ---------------------------------------------------------------------------
__global__ __launch_bounds__(256) void kBC(
        const float* __restrict__ ws,
        const float* __restrict__ mv_skip,
        const float* __restrict__ sc_src,
        const float* __restrict__ sc_skip,
        const float* __restrict__ pos_src,
        const float* __restrict__ pos_tgt,
        const int*   __restrict__ isrc,
        const float* __restrict__ W1_s,
        const float* __restrict__ b1_s,
        const float* __restrict__ W2_s,
        const float* __restrict__ b2_s,
        float* __restrict__ out) {
    __shared__ float sW1[HID][HID];        // [c][h]
    __shared__ float sW2T[SSC][HID + 4];   // [s][h] padded to 68
    __shared__ float sX[4][8][HID];        // per-wave cat X, reused as H
    __shared__ float sb1[HID], sb2[SSC];

    int tid = threadIdx.x;
    for (int e = tid; e < HID * HID; e += 256) sW1[e >> 6][e & 63] = W1_s[e];
    for (int e = tid; e < HID * SSC; e += 256) { int h = e >> 5, s = e & 31; sW2T[s][h] = W2_s[e]; }
    if (tid < HID) sb1[tid] = b1_s[tid];
    else if (tid < HID + SSC) sb2[tid - HID] = b2_s[tid - HID];
    __syncthreads();

    int lane = tid & 63, wv = tid >> 6;
    int d = lane >> 2, q = lane & 3;
    float wsk0 = ws[d], wsk1 = ws[MVD + d];
    const __half* proj = (const __half*)(ws + PROJ_OFFSET);

    int wid = (int)((blockIdx.x * blockDim.x + tid) >> 6);  // 0..8191
    int t0 = wid * 8;

    // --- precompute per-target srcs + normalized weights (lane k<8 holds edge k) ---
    int   srcv[8];
    float wnv[8];
    #pragma unroll
    for (int tl = 0; tl < 8; ++tl) {
        int t = t0 + tl;
        float w = 0.f; int s = 0;
        if (lane < KNN) {
            s = isrc[t * KNN + lane];
            float dx = pos_src[s * 3 + 0] - pos_tgt[t * 3 + 0];
            float dy = pos_src[s * 3 + 1] - pos_tgt[t * 3 + 1];
            float dz = pos_src[s * 3 + 2] - pos_tgt[t * 3 + 2];
            float d2 = fmaxf(dx * dx + dy * dy + dz * dz, 1e-16f);
            w = 1.0f / d2;
        }
        float den = w;
        den += __shfl_xor(den, 1);
        den += __shfl_xor(den, 2);
        den += __shfl_xor(den, 4);
        srcv[tl] = s;
        wnv[tl]  = w / den;   // lanes >=8: 0/0 never read
    }

    int kk = lane >> 3;   // scalar-gather edge 0..7
    int mm = lane & 7;    // scalar-gather float4 chunk 0..7

    // --- 4 pair-steps: mv gather+accumulate (16 in flight) + scalar gather/reduce ---
    #pragma unroll
    for (int pp = 0; pp < 4; ++pp) {
        int tA = t0 + pp * 2, tB = tA + 1;
        float wnA = wnv[pp * 2], wnB = wnv[pp * 2 + 1];
        int   sA  = srcv[pp * 2], sB = srcv[pp * 2 + 1];

        // mv gathers (coalesced 512B per edge row)
        uint2 g[16];
        #pragma unroll
        for (int k = 0; k < KNN; ++k) {
            int sk = __builtin_amdgcn_readlane(sA, k);
            g[k] = *(const uint2*)(proj + (size_t)sk * 256 + lane * 4);
        }
        #pragma unroll
        for (int k = 0; k < KNN; ++k) {
            int sk = __builtin_amdgcn_readlane(sB, k);
            g[8 + k] = *(const uint2*)(proj + (size_t)sk * 256 + lane * 4);
        }

        // scalar gathers: 64 lanes cover 8 edges x 8 chunks per target
        int   skA = __shfl(sA, kk),  skB = __shfl(sB, kk);
        float waE = __shfl(wnA, kk), wbE = __shfl(wnB, kk);
        float4 vA = *(const float4*)(sc_src + (size_t)skA * SSC + mm * 4);
        float4 vB = *(const float4*)(sc_src + (size_t)skB * SSC + mm * 4);
        float4 vS = make_float4(0.f, 0.f, 0.f, 0.f);
        if (lane < 16)
            vS = nt_load4(sc_skip + (size_t)(tA + (lane >> 3)) * SSC + (lane & 7) * 4);

        // mv accumulate
        float4 accA = make_float4(0.f, 0.f, 0.f, 0.f);
        float4 accB = make_float4(0.f, 0.f, 0.f, 0.f);
        #pragma unroll
        for (int k = 0; k < KNN; ++k) {
            float wk = __uint_as_float(__builtin_amdgcn_readlane(__float_as_uint(wnA), k));
            union { uint2 u; __half2 h[2]; } P; P.u = g[k];
            float2 lo = __half22float2(P.h[0]);
            float2 hi = __half22float2(P.h[1]);
            accA.x = fmaf(wk, lo.x, accA.x);
            accA.y = fmaf(wk, lo.y, accA.y);
            accA.z = fmaf(wk, hi.x, accA.z);
            accA.w = fmaf(wk, hi.y, accA.w);
        }
        #pragma unroll
        for (int k = 0; k < KNN; ++k) {
            float wk = __uint_as_float(__builtin_amdgcn_readlane(__float_as_uint(wnB), k));
            union { uint2 u; __half2 h[2]; } P; P.u = g[8 + k];
            float2 lo = __half22float2(P.h[0]);
            float2 hi = __half22float2(P.h[1]);
            accB.x = fmaf(wk, lo.x, accB.x);
            accB.y = fmaf(wk, lo.y, accB.y);
            accB.z = fmaf(wk, hi.x, accB.z);
            accB.w = fmaf(wk, hi.y, accB.w);
        }

        // scalar weighted reduce over edges (xor over k bits: 8,16,32)
        vA.x *= waE; vA.y *= waE; vA.z *= waE; vA.w *= waE;
        vB.x *= wbE; vB.y *= wbE; vB.z *= wbE; vB.w *= wbE;
        #pragma unroll
        for (int sft = 8; sft <= 32; sft <<= 1) {
            vA.x += __shfl_xor(vA.x, sft); vA.y += __shfl_xor(vA.y, sft);
            vA.z += __shfl_xor(vA.z, sft); vA.w += __shfl_xor(vA.w, sft);
            vB.x += __shfl_xor(vB.x, sft); vB.y += __shfl_xor(vB.y, sft);
            vB.z += __shfl_xor(vB.z, sft); vB.w += __shfl_xor(vB.w, sft);
        }
        if (lane < 8) {
            *(float4*)&sX[wv][pp * 2 + 0][lane * 4] = vA;
            *(float4*)&sX[wv][pp * 2 + 1][lane * 4] = vB;
        }
        if (lane < 16)
            *(float4*)&sX[wv][pp * 2 + (lane >> 3)][SSC + (lane & 7) * 4] = vS;

        // mv epilogue (NT: one-shot stream, keep L2 for the table)
        {
            const float4 u0 = nt_load4(mv_skip + (size_t)tA * 32 + q * 4);
            const float4 u1 = nt_load4(mv_skip + (size_t)tA * 32 + 16 + q * 4);
            float4 o;
            o.x = accA.x + fmaf(wsk0, u0.x, wsk1 * u1.x);
            o.y = accA.y + fmaf(wsk0, u0.y, wsk1 * u1.y);
            o.z = accA.z + fmaf(wsk0, u0.z, wsk1 * u1.z);
            o.w = accA.w + fmaf(wsk0, u0.w, wsk1 * u1.w);
            nt_store4(out + (size_t)tA * 256 + lane * 4, o);
        }
        {
            const float4 u0 = nt_load4(mv_skip + (size_t)tB * 32 + q * 4);
            const float4 u1 = nt_load4(mv_skip + (size_t)tB * 32 + 16 + q * 4);
            float4 o;
            o.x = accB.x + fmaf(wsk0, u0.x, wsk1 * u1.x);
            o.y = accB.y + fmaf(wsk0, u0.y, wsk1 * u1.y);
            o.z = accB.z + fmaf(wsk0, u0.z, wsk1 * u1.z);
            o.w = accB.w + fmaf(wsk0, u0.w, wsk1 * u1.w);
            nt_store4(out + (size_t)tB * 256 + lane * 4, o);
        }
    }

    // --- scalar GEMM1: h = lane, 8 targets ---
    float acc[8];
    #pragma unroll
    for (int t = 0; t < 8; ++t) acc[t] = 0.f;
    #pragma unroll 4
    for (int c4 = 0; c4 < 16; ++c4) {
        float w0 = sW1[c4 * 4 + 0][lane];
        float w1 = sW1[c4 * 4 + 1][lane];
        float w2 = sW1[c4 * 4 + 2][lane];
        float w3 = sW1[c4 * 4 + 3][lane];
        #pragma unroll
        for (int t = 0; t < 8; ++t) {
            float4 x4 = *(const float4*)&sX[wv][t][c4 * 4];   // broadcast
            acc[t] = fmaf(x4.x, w0, acc[t]);
            acc[t] = fmaf(x4.y, w1, acc[t]);
            acc[t] = fmaf(x4.z, w2, acc[t]);
            acc[t] = fmaf(x4.w, w3, acc[t]);
        }
    }
    {
        float bb = sb1[lane];
        #pragma unroll
        for (int t = 0; t < 8; ++t) {
            float h = gelu_tanh(acc[t] + bb);
            sX[wv][t][lane] = h;   // reuse sX as H (all GEMM1 reads complete)
        }
    }

    // --- scalar GEMM2: lane = th*32 + s; each lane does 4 targets x 1 s ---
    {
        int s = lane & 31, th = lane >> 5;
        float acc2[4];
        #pragma unroll
        for (int i = 0; i < 4; ++i) acc2[i] = 0.f;
        #pragma unroll 4
        for (int h4 = 0; h4 < 16; ++h4) {
            float4 w4 = *(const float4*)&sW2T[s][h4 * 4];
            #pragma unroll
            for (int i = 0; i < 4; ++i) {
                float4 x4 = *(const float4*)&sX[wv][th * 4 + i][h4 * 4];  // ~broadcast
                acc2[i] = fmaf(x4.x, w4.x, acc2[i]);
                acc2[i] = fmaf(x4.y, w4.y, acc2[i]);
                acc2[i] = fmaf(x4.z, w4.z, acc2[i]);
                acc2[i] = fmaf(x4.w, w4.w, acc2[i]);
            }
        }
        float* osc = out + OUT_MV_ELEMS;
        float bo = sb2[s];
        #pragma unroll
        for (int i = 0; i < 4; ++i) {
            int t = t0 + th * 4 + i;
            __builtin_nontemporal_store(acc2[i] + bo, &osc[(size_t)t * SSC + s]);
        }
    }
}

// ---------------------------------------------------------------------------
// Fallback pair (ws too small for proj table): f32 mv gather + separate scalar.
// ---------------------------------------------------------------------------
__global__ __launch_bounds__(256) void kBf_mv(
        const float* __restrict__ mv_src,
        const float* __restrict__ mv_skip,
        const float* __restrict__ pos_src,
        const float* __restrict__ pos_tgt,
        const int*   __restrict__ isrc,
        const float* __restrict__ W1_mv,
        const float* __restrict__ W2_mv,
        float* __restrict__ out) {
    __shared__ float sWeff[CMV + CSKIP][MVD];
    __shared__ float stage[4][256];
    int tid = threadIdx.x;
    for (int e = tid; e < (CMV + CSKIP) * MVD; e += 256) {
        int c = e >> 4, d = e & 15;
        float a = 0.f;
        #pragma unroll 8
        for (int h = 0; h < HID; ++h)
            a = fmaf(W1_mv[c * HID + h], W2_mv[h * MVD + d], a);
        sWeff[c][d] = a;
    }
    __syncthreads();

    int lane = tid & 63, wv = tid >> 6;
    int d = lane >> 2, q = lane & 3;
    float wcol[CMV + CSKIP];
    #pragma unroll
    for (int c = 0; c < CMV + CSKIP; ++c) wcol[c] = sWeff[c][d];

    int wid = (int)((blockIdx.x * blockDim.x + tid) >> 6);
    int nw  = (int)((gridDim.x * blockDim.x) >> 6);
    for (int t = wid; t < N_TGT; t += nw) {
        float w = 0.f; int src = 0;
        if (lane < KNN) {
            src = isrc[t * KNN + lane];
            float dx = pos_src[src * 3 + 0] - pos_tgt[t * 3 + 0];
            float dy = pos_src[src * 3 + 1] - pos_tgt[t * 3 + 1];
            float dz = pos_src[src * 3 + 2] - pos_tgt[t * 3 + 2];
            float d2 = fmaxf(dx * dx + dy * dy + dz * dz, 1e-16f);
            w = 1.0f / d2;
        }
        float denom = w;
        denom += __shfl_xor(denom, 1);
        denom += __shfl_xor(denom, 2);
        denom += __shfl_xor(denom, 4);
        denom = __shfl(denom, 0);
        float invd = 1.0f / denom;

        float4 acc = make_float4(0.f, 0.f, 0.f, 0.f);
        #pragma unroll
        for (int k = 0; k < KNN; ++k) {
            int   sk = __builtin_amdgcn_readlane(src, k);
            float wk = __uint_as_float(__builtin_amdgcn_readlane(__float_as_uint(w), k));
            float4 v = *(const float4*)(mv_src + (size_t)sk * 256 + lane * 4);
            acc.x = fmaf(wk, v.x, acc.x);
            acc.y = fmaf(wk, v.y, acc.y);
            acc.z = fmaf(wk, v.z, acc.z);
            acc.w = fmaf(wk, v.w, acc.w);
        }
        asm volatile("" ::: "memory");
        *(float4*)&stage[wv][lane * 4] = acc;
        asm volatile("s_waitcnt lgkmcnt(0)" ::: "memory");
        __builtin_amdgcn_sched_barrier(0);

        float4 o = make_float4(0.f, 0.f, 0.f, 0.f);
        #pragma unroll
        for (int c = 0; c < CMV; ++c) {
            float4 v = *(const float4*)&stage[wv][c * 16 + q * 4];
            o.x = fmaf(v.x, wcol[c], o.x);
            o.y = fmaf(v.y, wcol[c], o.y);
            o.z = fmaf(v.z, wcol[c], o.z);
            o.w = fmaf(v.w, wcol[c], o.w);
        }
        const float4 u0 = *(const float4*)(mv_skip + (size_t)t * 32 + q * 4);
        const float4 u1 = *(const float4*)(mv_skip + (size_t)t * 32 + 16 + q * 4);
        float4 r;
        r.x = fmaf(o.x, invd, fmaf(wcol[16], u0.x, wcol[17] * u1.x));
        r.y = fmaf(o.y, invd, fmaf(wcol[16], u0.y, wcol[17] * u1.y));
        r.z = fmaf(o.z, invd, fmaf(wcol[16], u0.z, wcol[17] * u1.z));
        r.w = fmaf(o.w, invd, fmaf(wcol[16], u0.w, wcol[17] * u1.w));
        *(float4*)(out + (size_t)t * 256 + lane * 4) = r;
    }
}

__global__ __launch_bounds__(256) void kC_scalar(
        const float* __restrict__ sc_src,
        const float* __restrict__ sc_skip,
        const float* __restrict__ pos_src,
        const float* __restrict__ pos_tgt,
        const int*   __restrict__ isrc,
        const float* __restrict__ W1_s,
        const float* __restrict__ b1_s,
        const float* __restrict__ W2_s,
        const float* __restrict__ b2_s,
        float* __restrict__ out) {
    __shared__ float sW1[HID * HID];
    __shared__ float sW2T[SSC][68];
    __shared__ float sXT[HID][68];
    __shared__ float sH[64][68];
    __shared__ float swgt[64][9];
    __shared__ int   ssrcl[64][9];
    __shared__ float sb1[HID], sb2[SSC];

    int tid = threadIdx.x;
    #pragma unroll
    for (int r = 0; r < 4; ++r) {
        float4 v = *(const float4*)(W1_s + (r * 256 + tid) * 4);
        *(float4*)&sW1[(r * 256 + tid) * 4] = v;
    }
    for (int e = tid; e < HID * SSC; e += 256) {
        int h = e >> 5, s = e & 31;
        sW2T[s][h] = W2_s[e];
    }
    if (tid < HID) sb1[tid] = b1_s[tid];
    else if (tid < HID + SSC) sb2[tid - HID] = b2_s[tid - HID];

    int t0 = blockIdx.x * 64;
    if (tid < 64) {
        int t = t0 + tid;
        float ptx = pos_tgt[t * 3 + 0], pty = pos_tgt[t * 3 + 1], ptz = pos_tgt[t * 3 + 2];
        int4 e0 = *(const int4*)(isrc + t * KNN);
        int4 e1 = *(const int4*)(isrc + t * KNN + 4);
        int sk[KNN] = {e0.x, e0.y, e0.z, e0.w, e1.x, e1.y, e1.z, e1.w};
        float wk[KNN];
        float denom = 0.f;
        #pragma unroll
        for (int k = 0; k < KNN; ++k) {
            int s = sk[k];
            float dx = pos_src[s * 3 + 0] - ptx;
            float dy = pos_src[s * 3 + 1] - pty;
            float dz = pos_src[s * 3 + 2] - ptz;
            float d2 = fmaxf(dx * dx + dy * dy + dz * dz, 1e-16f);
            wk[k] = 1.0f / d2;
            denom += wk[k];
        }
        float invd = 1.0f / denom;
        #pragma unroll
        for (int k = 0; k < KNN; ++k) {
            swgt[tid][k] = wk[k] * invd;
            ssrcl[tid][k] = sk[k];
        }
    }
    __syncthreads();

    {
        int wv = tid >> 6, lane = tid & 63;
        int k = lane >> 3;
        int m = lane & 7;
        for (int i = 0; i < 16; i += 4) {
            int tb = wv * 16 + i;
            float4 v[4]; float wn4[4];
            #pragma unroll
            for (int j = 0; j < 4; ++j) {
                int tl = tb + j;
                wn4[j] = swgt[tl][k];
                int sk = ssrcl[tl][k];
                v[j] = *(const float4*)(sc_src + (size_t)sk * SSC + m * 4);
            }
            float4 u;
            if (lane < 32)
                u = *(const float4*)(sc_skip + (size_t)(t0 + tb + k) * SSC + m * 4);
            #pragma unroll
            for (int j = 0; j < 4; ++j) {
                float4 a = v[j]; float wn = wn4[j];
                a.x *= wn; a.y *= wn; a.z *= wn; a.w *= wn;
                #pragma unroll
                for (int sft = 8; sft <= 32; sft <<= 1) {
                    a.x += __shfl_xor(a.x, sft);
                    a.y += __shfl_xor(a.y, sft);
                    a.z += __shfl_xor(a.z, sft);
                    a.w += __shfl_xor(a.w, sft);
                }
                if (lane < 8) {
                    sXT[4 * lane + 0][tb + j] = a.x;
                    sXT[4 * lane + 1][tb + j] = a.y;
                    sXT[4 * lane + 2][tb + j] = a.z;
                    sXT[4 * lane + 3][tb + j] = a.w;
                }
            }
            if (lane < 32) {
                sXT[SSC + 4 * m + 0][tb + k] = u.x;
                sXT[SSC + 4 * m + 1][tb + k] = u.y;
                sXT[SSC + 4 * m + 2][tb + k] = u.z;
                sXT[SSC + 4 * m + 3][tb + k] = u.w;
            }
        }
    }
    __syncthreads();

    int wv = tid >> 6;
    int lane = tid & 63;
    int tr4 = lane >> 4;
    int hc  = lane & 15;
    int tbase = wv * 16 + tr4 * 4;
    float acc[4][4];
    #pragma unroll
    for (int i = 0; i < 4; ++i)
        #pragma unroll
        for (int j = 0; j < 4; ++j) acc[i][j] = 0.f;

    #pragma unroll 2
    for (int c = 0; c < HID; ++c) {
        float4 xv = *(const float4*)&sXT[c][tbase];
        float4 wv4 = *(const float4*)&sW1[c * HID + hc * 4];
        acc[0][0] = fmaf(xv.x, wv4.x, acc[0][0]);
        acc[0][1] = fmaf(xv.x, wv4.y, acc[0][1]);
        acc[0][2] = fmaf(xv.x, wv4.z, acc[0][2]);
        acc[0][3] = fmaf(xv.x, wv4.w, acc[0][3]);
        acc[1][0] = fmaf(xv.y, wv4.x, acc[1][0]);
        acc[1][1] = fmaf(xv.y, wv4.y, acc[1][1]);
        acc[1][2] = fmaf(xv.y, wv4.z, acc[1][2]);
        acc[1][3] = fmaf(xv.y, wv4.w, acc[1][3]);
        acc[2][0] = fmaf(xv.z, wv4.x, acc[2][0]);
        acc[2][1] = fmaf(xv.z, wv4.y, acc[2][1]);
        acc[2][2] = fmaf(xv.z, wv4.z, acc[2][2]);
        acc[2][3] = fmaf(xv.z, wv4.w, acc[2][3]);
        acc[3][0] = fmaf(xv.w, wv4.x, acc[3][0]);
        acc[3][1] = fmaf(xv.w, wv4.y, acc[3][1]);
        acc[3][2] = fmaf(xv.w, wv4.z, acc[3][2]);
        acc[3][3] = fmaf(xv.w, wv4.w, acc[3][3]);
    }
    {
        float b0 = sb1[hc * 4 + 0], b1 = sb1[hc * 4 + 1];
        float b2 = sb1[hc * 4 + 2], b3 = sb1[hc * 4 + 3];
        #pragma unroll
        for (int i = 0; i < 4; ++i) {
            float4 hv;
            hv.x = gelu_tanh(acc[i][0] + b0);
            hv.y = gelu_tanh(acc[i][1] + b1);
            hv.z = gelu_tanh(acc[i][2] + b2);
            hv.w = gelu_tanh(acc[i][3] + b3);
            *(float4*)&sH[tbase + i][hc * 4] = hv;
        }
    }
    __syncthreads();

    int sc16 = lane & 15;
    float acc2[4][2];
    #pragma unroll
    for (int i = 0; i < 4; ++i) { acc2[i][0] = 0.f; acc2[i][1] = 0.f; }
    #pragma unroll 2
    for (int hh = 0; hh < 16; ++hh) {
        float4 wa = *(const float4*)&sW2T[sc16 * 2 + 0][hh * 4];
        float4 wb = *(const float4*)&sW2T[sc16 * 2 + 1][hh * 4];
        #pragma unroll
        for (int i = 0; i < 4; ++i) {
            float4 hv = *(const float4*)&sH[tbase + i][hh * 4];
            acc2[i][0] = fmaf(hv.x, wa.x, acc2[i][0]);
            acc2[i][0] = fmaf(hv.y, wa.y, acc2[i][0]);
            acc2[i][0] = fmaf(hv.z, wa.z, acc2[i][0]);
            acc2[i][0] = fmaf(hv.w, wa.w, acc2[i][0]);
            acc2[i][1] = fmaf(hv.x, wb.x, acc2[i][1]);
            acc2[i][1] = fmaf(hv.y, wb.y, acc2[i][1]);
            acc2[i][1] = fmaf(hv.z, wb.z, acc2[i][1]);
            acc2[i][1] = fmaf(hv.w, wb.w, acc2[i][1]);
        }
    }
    float* osc = out + OUT_MV_ELEMS;
    float bb0 = sb2[sc16 * 2 + 0], bb1 = sb2[sc16 * 2 + 1];
    #pragma unroll
    for (int i = 0; i < 4; ++i) {
        int t = t0 + tbase + i;
        float2 r = make_float2(acc2[i][0] + bb0, acc2[i][1] + bb1);
        *(float2*)&osc[(size_t)t * SSC + sc16 * 2] = r;
    }
}

// ---------------------------------------------------------------------------
extern "C" void kernel_launch(void* const* d_in, const int* in_sizes, int n_in,
                              void* d_out, int out_size, void* d_ws, size_t ws_size,
                              hipStream_t stream) {
    const float* mv_src   = (const float*)d_in[0];
    const float* mv_skip  = (const float*)d_in[1];
    const float* sc_src   = (const float*)d_in[2];
    const float* sc_skip  = (const float*)d_in[3];
    const float* pos_src  = (const float*)d_in[4];
    const float* pos_tgt  = (const float*)d_in[5];
    const int*   isrc     = (const int*)d_in[6];
    // d_in[7] = interp_target: structurally repeat(arange(N_TGT), K) -- unused
    const float* W1_mv    = (const float*)d_in[8];
    const float* W2_mv    = (const float*)d_in[9];
    const float* W1_s     = (const float*)d_in[10];
    const float* b1_s     = (const float*)d_in[11];
    const float* W2_s     = (const float*)d_in[12];
    const float* b2_s     = (const float*)d_in[13];
    float* out = (float*)d_out;
    float* ws  = (float*)d_ws;

    size_t need_ws_bytes = PROJ_OFFSET * sizeof(float) + (size_t)N_SRC * 256 * sizeof(__half);
    if (ws_size >= need_ws_bytes) {
        hipLaunchKernelGGL(kA_preproject, dim3(512), dim3(256), 0, stream,
                           mv_src, W1_mv, W2_mv, ws);
        hipLaunchKernelGGL(kBC, dim3(2048), dim3(256), 0, stream,
                           ws, mv_skip, sc_src, sc_skip, pos_src, pos_tgt, isrc,
                           W1_s, b1_s, W2_s, b2_s, out);
    } else {
        hipLaunchKernelGGL(kBf_mv, dim3(2048), dim3(256), 0, stream,
                           mv_src, mv_skip, pos_src, pos_tgt, isrc, W1_mv, W2_mv, out);
        hipLaunchKernelGGL(kC_scalar, dim3(N_TGT / 64), dim3(256), 0, stream,
                           sc_src, sc_skip, pos_src, pos_tgt, isrc,
                           W1_s, b1_s, W2_s, b2_s, out);
    }
}

// Round 5
// 215.226 us; speedup vs baseline: 1.0075x; 1.0075x over previous
//
#include <hip/hip_runtime.h>
#include <hip/hip_fp16.h>

#define N_SRC 16384
#define N_TGT 65536
#define KNN 8
#define CMV 16
#define CSKIP 2
#define SSC 32
#define HID 64
#define MVD 16

#define OUT_MV_ELEMS (N_TGT * CMV * MVD)   // 16777216 floats
#define PROJ_OFFSET 512                    // floats reserved at start of ws (skip Weff rows)
// fp16 proj table at ws + PROJ_OFFSET: N_SRC x 256 halves (512 B/row, 8 MB)

typedef float vf4 __attribute__((ext_vector_type(4)));

__device__ __forceinline__ float4 nt_load4(const float* p) {
    vf4 v = __builtin_nontemporal_load((const vf4*)p);
    return make_float4(v.x, v.y, v.z, v.w);
}
__device__ __forceinline__ void nt_store4(float* p, float4 o) {
    vf4 v; v.x = o.x; v.y = o.y; v.z = o.z; v.w = o.w;
    __builtin_nontemporal_store(v, (vf4*)p);
}

__device__ __forceinline__ float gelu_tanh(float x) {
    const float k0 = 0.7978845608028654f;  // sqrt(2/pi)
    const float k1 = 0.044715f;
    float yy = k0 * (x + k1 * x * x * x);
    return 0.5f * x * (1.0f + tanhf(yy));
}

// ---------------------------------------------------------------------------
// Kernel A: mv_proj[s][d][i] = sum_c mv_src[s][c][i] * W_eff[c][d] (c<16), fp16.
// W_eff = W1_mv @ W2_mv (mv path fully linear).  Block 0 writes skip rows
// (c=16,17) of W_eff to ws[0..31] (f32).
// ---------------------------------------------------------------------------
__global__ __launch_bounds__(256) void kA_preproject(
        const float* __restrict__ mv_src,
        const float* __restrict__ W1_mv,
        const float* __restrict__ W2_mv,
        float* __restrict__ ws) {
    __shared__ float sWeff[CMV][MVD];
    int tid = threadIdx.x;
    {
        int c = tid >> 4, d = tid & 15;
        float a = 0.f;
        #pragma unroll 8
        for (int h = 0; h < HID; ++h)
            a = fmaf(W1_mv[c * HID + h], W2_mv[h * MVD + d], a);
        sWeff[c][d] = a;
    }
    if (blockIdx.x == 0 && tid < 32) {
        int j = tid >> 4, d = tid & 15;
        float a = 0.f;
        #pragma unroll 8
        for (int h = 0; h < HID; ++h)
            a = fmaf(W1_mv[(CMV + j) * HID + h], W2_mv[h * MVD + d], a);
        ws[j * MVD + d] = a;
    }
    __syncthreads();

    int lane = tid & 63;
    int d = lane >> 2, q = lane & 3;
    float wcol[CMV];
    #pragma unroll
    for (int c = 0; c < CMV; ++c) wcol[c] = sWeff[c][d];

    __half* proj = (__half*)(ws + PROJ_OFFSET);
    int wid = (int)((blockIdx.x * blockDim.x + tid) >> 6);
    int nw  = (int)((gridDim.x * blockDim.x) >> 6);
    for (int s = wid; s < N_SRC; s += nw) {
        const float* row = mv_src + (size_t)s * 256;
        float4 o = make_float4(0.f, 0.f, 0.f, 0.f);
        #pragma unroll
        for (int c = 0; c < CMV; ++c) {
            float4 v = *(const float4*)(row + c * 16 + q * 4);
            o.x = fmaf(v.x, wcol[c], o.x);
            o.y = fmaf(v.y, wcol[c], o.y);
            o.z = fmaf(v.z, wcol[c], o.z);
            o.w = fmaf(v.w, wcol[c], o.w);
        }
        union { __half2 h[2]; uint2 u; } P;
        P.h[0] = __floats2half2_rn(o.x, o.y);
        P.h[1] = __floats2half2_rn(o.z, o.w);
        *(uint2*)(proj + (size_t)s * 256 + lane * 4) = P.u;
    }
}

// ---------------------------------------------------------------------------
// Kernel B: mv output.  Software-pipelined gathers: pair p+1's 16 loads are
// issued BEFORE pair p is consumed (double buffer gA/gB), with a
// sched_barrier(0) fence so the compiler cannot re-fuse issue+consume into
// small load batches (round-3 kB compiled to 36 VGPR => only ~5 loads in
// flight).  Target: 16-32 outstanding loads per wave continuously.
// NT stores for out + NT loads for mv_skip keep the proj table L2-resident.
// ---------------------------------------------------------------------------
#define KB_ISSUE(buf, PP) do {                                               \
    int _sA = srcv[2 * (PP)], _sB = srcv[2 * (PP) + 1];                      \
    _Pragma("unroll")                                                        \
    for (int k = 0; k < 8; ++k) {                                            \
        int _sk = __builtin_amdgcn_readlane(_sA, k);                         \
        buf[k] = *(const uint2*)(proj + (size_t)_sk * 256 + lane * 4);       \
    }                                                                        \
    _Pragma("unroll")                                                        \
    for (int k = 0; k < 8; ++k) {                                            \
        int _sk = __builtin_amdgcn_readlane(_sB, k);                         \
        buf[8 + k] = *(const uint2*)(proj + (size_t)_sk * 256 + lane * 4);   \
    }                                                                        \
} while (0)

#define KB_MATHSTORE(buf, PP) do {                                           \
    float _wnA = wnv[2 * (PP)], _wnB = wnv[2 * (PP) + 1];                    \
    float4 accA = make_float4(0.f, 0.f, 0.f, 0.f);                           \
    float4 accB = make_float4(0.f, 0.f, 0.f, 0.f);                           \
    _Pragma("unroll")                                                        \
    for (int k = 0; k < 8; ++k) {                                            \
        float wk = __uint_as_float(                                          \
            __builtin_amdgcn_readlane(__float_as_uint(_wnA), k));            \
        union { uint2 u; __half2 h[2]; } P; P.u = buf[k];                    \
        float2 lo = __half22float2(P.h[0]);                                  \
        float2 hi = __half22float2(P.h[1]);                                  \
        accA.x = fmaf(wk, lo.x, accA.x);                                     \
        accA.y = fmaf(wk, lo.y, accA.y);                                     \
        accA.z = fmaf(wk, hi.x, accA.z);                                     \
        accA.w = fmaf(wk, hi.y, accA.w);                                     \
    }                                                                        \
    _Pragma("unroll")                                                        \
    for (int k = 0; k < 8; ++k) {                                            \
        float wk = __uint_as_float(                                          \
            __builtin_amdgcn_readlane(__float_as_uint(_wnB), k));            \
        union { uint2 u; __half2 h[2]; } P; P.u = buf[8 + k];                \
        float2 lo = __half22float2(P.h[0]);                                  \
        float2 hi = __half22float2(P.h[1]);                                  \
        accB.x = fmaf(wk, lo.x, accB.x);                                     \
        accB.y = fmaf(wk, lo.y, accB.y);                                     \
        accB.z = fmaf(wk, hi.x, accB.z);                                     \
        accB.w = fmaf(wk, hi.y, accB.w);                                     \
    }                                                                        \
    int _tA = t0 + 2 * (PP), _tB = _tA + 1;                                  \
    float4 o;                                                                \
    o.x = accA.x + fmaf(wsk0, u0A.x, wsk1 * u1A.x);                          \
    o.y = accA.y + fmaf(wsk0, u0A.y, wsk1 * u1A.y);                          \
    o.z = accA.z + fmaf(wsk0, u0A.z, wsk1 * u1A.z);                          \
    o.w = accA.w + fmaf(wsk0, u0A.w, wsk1 * u1A.w);                          \
    nt_store4(out + (size_t)_tA * 256 + lane * 4, o);                        \
    o.x = accB.x + fmaf(wsk0, u0B.x, wsk1 * u1B.x);                          \
    o.y = accB.y + fmaf(wsk0, u0B.y, wsk1 * u1B.y);                          \
    o.z = accB.z + fmaf(wsk0, u0B.z, wsk1 * u1B.z);                          \
    o.w = accB.w + fmaf(wsk0, u0B.w, wsk1 * u1B.w);                          \
    nt_store4(out + (size_t)_tB * 256 + lane * 4, o);                        \
} while (0)

__global__ __launch_bounds__(256, 4) void kB_mv(
        const float* __restrict__ ws,
        const float* __restrict__ mv_skip,
        const float* __restrict__ pos_src,
        const float* __restrict__ pos_tgt,
        const int*   __restrict__ isrc,
        float* __restrict__ out) {
    int tid = threadIdx.x;
    int lane = tid & 63;
    int dd = lane >> 2, q = lane & 3;
    float wsk0 = ws[dd], wsk1 = ws[MVD + dd];
    const __half* proj = (const __half*)(ws + PROJ_OFFSET);

    int wid = (int)((blockIdx.x * blockDim.x + tid) >> 6);  // 0..8191
    int t0 = wid * 8;

    // --- per-target normalized weights + source ids (lane k<8 holds edge k) ---
    int   srcv[8];
    float wnv[8];
    #pragma unroll
    for (int tl = 0; tl < 8; ++tl) {
        int t = t0 + tl;
        float w = 0.f; int s = 0;
        if (lane < KNN) {
            s = isrc[t * KNN + lane];
            float dx = pos_src[s * 3 + 0] - pos_tgt[t * 3 + 0];
            float dy = pos_src[s * 3 + 1] - pos_tgt[t * 3 + 1];
            float dz = pos_src[s * 3 + 2] - pos_tgt[t * 3 + 2];
            float d2 = fmaxf(dx * dx + dy * dy + dz * dz, 1e-16f);
            w = 1.0f / d2;
        }
        float den = w;
        den += __shfl_xor(den, 1);
        den += __shfl_xor(den, 2);
        den += __shfl_xor(den, 4);
        srcv[tl] = s;
        wnv[tl]  = w / den;   // lanes >=8: 0/0 never read
    }

    uint2 gA[16], gB[16];
    float4 u0A, u1A, u0B, u1B;

    KB_ISSUE(gA, 0);
    #pragma unroll
    for (int pp = 0; pp < 4; ++pp) {
        // issue next pair's gathers (into the other buffer)
        if (pp == 0)      KB_ISSUE(gB, 1);
        else if (pp == 1) KB_ISSUE(gA, 2);
        else if (pp == 2) KB_ISSUE(gB, 3);
        // skip-stream loads for the CURRENT pair (overlap with accumulate)
        {
            int tA = t0 + 2 * pp, tB = tA + 1;
            u0A = nt_load4(mv_skip + (size_t)tA * 32 + q * 4);
            u1A = nt_load4(mv_skip + (size_t)tA * 32 + 16 + q * 4);
            u0B = nt_load4(mv_skip + (size_t)tB * 32 + q * 4);
            u1B = nt_load4(mv_skip + (size_t)tB * 32 + 16 + q * 4);
        }
        __builtin_amdgcn_sched_barrier(0);   // keep issue region above consume
        if ((pp & 1) == 0) KB_MATHSTORE(gA, pp);
        else               KB_MATHSTORE(gB, pp);
    }
}

// ---------------------------------------------------------------------------
// Fallback (ws too small for proj table): f32 mv gather + W_eff via LDS stage.
// ---------------------------------------------------------------------------
__global__ __launch_bounds__(256) void kBf_mv(
        const float* __restrict__ mv_src,
        const float* __restrict__ mv_skip,
        const float* __restrict__ pos_src,
        const float* __restrict__ pos_tgt,
        const int*   __restrict__ isrc,
        const float* __restrict__ W1_mv,
        const float* __restrict__ W2_mv,
        float* __restrict__ out) {
    __shared__ float sWeff[CMV + CSKIP][MVD];
    __shared__ float stage[4][256];
    int tid = threadIdx.x;
    for (int e = tid; e < (CMV + CSKIP) * MVD; e += 256) {
        int c = e >> 4, d = e & 15;
        float a = 0.f;
        #pragma unroll 8
        for (int h = 0; h < HID; ++h)
            a = fmaf(W1_mv[c * HID + h], W2_mv[h * MVD + d], a);
        sWeff[c][d] = a;
    }
    __syncthreads();

    int lane = tid & 63, wv = tid >> 6;
    int d = lane >> 2, q = lane & 3;
    float wcol[CMV + CSKIP];
    #pragma unroll
    for (int c = 0; c < CMV + CSKIP; ++c) wcol[c] = sWeff[c][d];

    int wid = (int)((blockIdx.x * blockDim.x + tid) >> 6);
    int nw  = (int)((gridDim.x * blockDim.x) >> 6);
    for (int t = wid; t < N_TGT; t += nw) {
        float w = 0.f; int src = 0;
        if (lane < KNN) {
            src = isrc[t * KNN + lane];
            float dx = pos_src[src * 3 + 0] - pos_tgt[t * 3 + 0];
            float dy = pos_src[src * 3 + 1] - pos_tgt[t * 3 + 1];
            float dz = pos_src[src * 3 + 2] - pos_tgt[t * 3 + 2];
            float d2 = fmaxf(dx * dx + dy * dy + dz * dz, 1e-16f);
            w = 1.0f / d2;
        }
        float denom = w;
        denom += __shfl_xor(denom, 1);
        denom += __shfl_xor(denom, 2);
        denom += __shfl_xor(denom, 4);
        denom = __shfl(denom, 0);
        float invd = 1.0f / denom;

        float4 acc = make_float4(0.f, 0.f, 0.f, 0.f);
        #pragma unroll
        for (int k = 0; k < KNN; ++k) {
            int   sk = __builtin_amdgcn_readlane(src, k);
            float wk = __uint_as_float(__builtin_amdgcn_readlane(__float_as_uint(w), k));
            float4 v = *(const float4*)(mv_src + (size_t)sk * 256 + lane * 4);
            acc.x = fmaf(wk, v.x, acc.x);
            acc.y = fmaf(wk, v.y, acc.y);
            acc.z = fmaf(wk, v.z, acc.z);
            acc.w = fmaf(wk, v.w, acc.w);
        }
        asm volatile("" ::: "memory");
        *(float4*)&stage[wv][lane * 4] = acc;
        asm volatile("s_waitcnt lgkmcnt(0)" ::: "memory");
        __builtin_amdgcn_sched_barrier(0);

        float4 o = make_float4(0.f, 0.f, 0.f, 0.f);
        #pragma unroll
        for (int c = 0; c < CMV; ++c) {
            float4 v = *(const float4*)&stage[wv][c * 16 + q * 4];
            o.x = fmaf(v.x, wcol[c], o.x);
            o.y = fmaf(v.y, wcol[c], o.y);
            o.z = fmaf(v.z, wcol[c], o.z);
            o.w = fmaf(v.w, wcol[c], o.w);
        }
        const float4 u0 = *(const float4*)(mv_skip + (size_t)t * 32 + q * 4);
        const float4 u1 = *(const float4*)(mv_skip + (size_t)t * 32 + 16 + q * 4);
        float4 r;
        r.x = fmaf(o.x, invd, fmaf(wcol[16], u0.x, wcol[17] * u1.x));
        r.y = fmaf(o.y, invd, fmaf(wcol[16], u0.y, wcol[17] * u1.y));
        r.z = fmaf(o.z, invd, fmaf(wcol[16], u0.z, wcol[17] * u1.z));
        r.w = fmaf(o.w, invd, fmaf(wcol[16], u0.w, wcol[17] * u1.w));
        *(float4*)(out + (size_t)t * 256 + lane * 4) = r;
    }
}

// ---------------------------------------------------------------------------
// Kernel C: scalar path (round-3 version, unchanged: no counter evidence
// against it; one change per round).
// ---------------------------------------------------------------------------
__global__ __launch_bounds__(256) void kC_scalar(
        const float* __restrict__ sc_src,
        const float* __restrict__ sc_skip,
        const float* __restrict__ pos_src,
        const float* __restrict__ pos_tgt,
        const int*   __restrict__ isrc,
        const float* __restrict__ W1_s,
        const float* __restrict__ b1_s,
        const float* __restrict__ W2_s,
        const float* __restrict__ b2_s,
        float* __restrict__ out) {
    __shared__ float sW1[HID * HID];
    __shared__ float sW2T[SSC][68];
    __shared__ float sXT[HID][68];
    __shared__ float sH[64][68];
    __shared__ float swgt[64][9];
    __shared__ int   ssrcl[64][9];
    __shared__ float sb1[HID], sb2[SSC];

    int tid = threadIdx.x;
    #pragma unroll
    for (int r = 0; r < 4; ++r) {
        float4 v = *(const float4*)(W1_s + (r * 256 + tid) * 4);
        *(float4*)&sW1[(r * 256 + tid) * 4] = v;
    }
    for (int e = tid; e < HID * SSC; e += 256) {
        int h = e >> 5, s = e & 31;
        sW2T[s][h] = W2_s[e];
    }
    if (tid < HID) sb1[tid] = b1_s[tid];
    else if (tid < HID + SSC) sb2[tid - HID] = b2_s[tid - HID];

    int t0 = blockIdx.x * 64;
    if (tid < 64) {
        int t = t0 + tid;
        float ptx = pos_tgt[t * 3 + 0], pty = pos_tgt[t * 3 + 1], ptz = pos_tgt[t * 3 + 2];
        int4 e0 = *(const int4*)(isrc + t * KNN);
        int4 e1 = *(const int4*)(isrc + t * KNN + 4);
        int sk[KNN] = {e0.x, e0.y, e0.z, e0.w, e1.x, e1.y, e1.z, e1.w};
        float wk[KNN];
        float denom = 0.f;
        #pragma unroll
        for (int k = 0; k < KNN; ++k) {
            int s = sk[k];
            float dx = pos_src[s * 3 + 0] - ptx;
            float dy = pos_src[s * 3 + 1] - pty;
            float dz = pos_src[s * 3 + 2] - ptz;
            float d2 = fmaxf(dx * dx + dy * dy + dz * dz, 1e-16f);
            wk[k] = 1.0f / d2;
            denom += wk[k];
        }
        float invd = 1.0f / denom;
        #pragma unroll
        for (int k = 0; k < KNN; ++k) {
            swgt[tid][k] = wk[k] * invd;
            ssrcl[tid][k] = sk[k];
        }
    }
    __syncthreads();

    {
        int wv = tid >> 6, lane = tid & 63;
        int k = lane >> 3;
        int m = lane & 7;
        for (int i = 0; i < 16; i += 4) {
            int tb = wv * 16 + i;
            float4 v[4]; float wn4[4];
            #pragma unroll
            for (int j = 0; j < 4; ++j) {
                int tl = tb + j;
                wn4[j] = swgt[tl][k];
                int sk = ssrcl[tl][k];
                v[j] = *(const float4*)(sc_src + (size_t)sk * SSC + m * 4);
            }
            float4 u;
            if (lane < 32)
                u = *(const float4*)(sc_skip + (size_t)(t0 + tb + k) * SSC + m * 4);
            #pragma unroll
            for (int j = 0; j < 4; ++j) {
                float4 a = v[j]; float wn = wn4[j];
                a.x *= wn; a.y *= wn; a.z *= wn; a.w *= wn;
                #pragma unroll
                for (int sft = 8; sft <= 32; sft <<= 1) {
                    a.x += __shfl_xor(a.x, sft);
                    a.y += __shfl_xor(a.y, sft);
                    a.z += __shfl_xor(a.z, sft);
                    a.w += __shfl_xor(a.w, sft);
                }
                if (lane < 8) {
                    sXT[4 * lane + 0][tb + j] = a.x;
                    sXT[4 * lane + 1][tb + j] = a.y;
                    sXT[4 * lane + 2][tb + j] = a.z;
                    sXT[4 * lane + 3][tb + j] = a.w;
                }
            }
            if (lane < 32) {
                sXT[SSC + 4 * m + 0][tb + k] = u.x;
                sXT[SSC + 4 * m + 1][tb + k] = u.y;
                sXT[SSC + 4 * m + 2][tb + k] = u.z;
                sXT[SSC + 4 * m + 3][tb + k] = u.w;
            }
        }
    }
    __syncthreads();

    int wv = tid >> 6;
    int lane = tid & 63;
    int tr4 = lane >> 4;
    int hc  = lane & 15;
    int tbase = wv * 16 + tr4 * 4;
    float acc[4][4];
    #pragma unroll
    for (int i = 0; i < 4; ++i)
        #pragma unroll
        for (int j = 0; j < 4; ++j) acc[i][j] = 0.f;

    #pragma unroll 2
    for (int c = 0; c < HID; ++c) {
        float4 xv = *(const float4*)&sXT[c][tbase];
        float4 wv4 = *(const float4*)&sW1[c * HID + hc * 4];
        acc[0][0] = fmaf(xv.x, wv4.x, acc[0][0]);
        acc[0][1] = fmaf(xv.x, wv4.y, acc[0][1]);
        acc[0][2] = fmaf(xv.x, wv4.z, acc[0][2]);
        acc[0][3] = fmaf(xv.x, wv4.w, acc[0][3]);
        acc[1][0] = fmaf(xv.y, wv4.x, acc[1][0]);
        acc[1][1] = fmaf(xv.y, wv4.y, acc[1][1]);
        acc[1][2] = fmaf(xv.y, wv4.z, acc[1][2]);
        acc[1][3] = fmaf(xv.y, wv4.w, acc[1][3]);
        acc[2][0] = fmaf(xv.z, wv4.x, acc[2][0]);
        acc[2][1] = fmaf(xv.z, wv4.y, acc[2][1]);
        acc[2][2] = fmaf(xv.z, wv4.z, acc[2][2]);
        acc[2][3] = fmaf(xv.z, wv4.w, acc[2][3]);
        acc[3][0] = fmaf(xv.w, wv4.x, acc[3][0]);
        acc[3][1] = fmaf(xv.w, wv4.y, acc[3][1]);
        acc[3][2] = fmaf(xv.w, wv4.z, acc[3][2]);
        acc[3][3] = fmaf(xv.w, wv4.w, acc[3][3]);
    }
    {
        float b0 = sb1[hc * 4 + 0], b1 = sb1[hc * 4 + 1];
        float b2 = sb1[hc * 4 + 2], b3 = sb1[hc * 4 + 3];
        #pragma unroll
        for (int i = 0; i < 4; ++i) {
            float4 hv;
            hv.x = gelu_tanh(acc[i][0] + b0);
            hv.y = gelu_tanh(acc[i][1] + b1);
            hv.z = gelu_tanh(acc[i][2] + b2);
            hv.w = gelu_tanh(acc[i][3] + b3);
            *(float4*)&sH[tbase + i][hc * 4] = hv;
        }
    }
    __syncthreads();

    int sc16 = lane & 15;
    float acc2[4][2];
    #pragma unroll
    for (int i = 0; i < 4; ++i) { acc2[i][0] = 0.f; acc2[i][1] = 0.f; }
    #pragma unroll 2
    for (int hh = 0; hh < 16; ++hh) {
        float4 wa = *(const float4*)&sW2T[sc16 * 2 + 0][hh * 4];
        float4 wb = *(const float4*)&sW2T[sc16 * 2 + 1][hh * 4];
        #pragma unroll
        for (int i = 0; i < 4; ++i) {
            float4 hv = *(const float4*)&sH[tbase + i][hh * 4];
            acc2[i][0] = fmaf(hv.x, wa.x, acc2[i][0]);
            acc2[i][0] = fmaf(hv.y, wa.y, acc2[i][0]);
            acc2[i][0] = fmaf(hv.z, wa.z, acc2[i][0]);
            acc2[i][0] = fmaf(hv.w, wa.w, acc2[i][0]);
            acc2[i][1] = fmaf(hv.x, wb.x, acc2[i][1]);
            acc2[i][1] = fmaf(hv.y, wb.y, acc2[i][1]);
            acc2[i][1] = fmaf(hv.z, wb.z, acc2[i][1]);
            acc2[i][1] = fmaf(hv.w, wb.w, acc2[i][1]);
        }
    }
    float* osc = out + OUT_MV_ELEMS;
    float bb0 = sb2[sc16 * 2 + 0], bb1 = sb2[sc16 * 2 + 1];
    #pragma unroll
    for (int i = 0; i < 4; ++i) {
        int t = t0 + tbase + i;
        float2 r = make_float2(acc2[i][0] + bb0, acc2[i][1] + bb1);
        *(float2*)&osc[(size_t)t * SSC + sc16 * 2] = r;
    }
}

// ---------------------------------------------------------------------------
extern "C" void kernel_launch(void* const* d_in, const int* in_sizes, int n_in,
                              void* d_out, int out_size, void* d_ws, size_t ws_size,
                              hipStream_t stream) {
    const float* mv_src   = (const float*)d_in[0];
    const float* mv_skip  = (const float*)d_in[1];
    const float* sc_src   = (const float*)d_in[2];
    const float* sc_skip  = (const float*)d_in[3];
    const float* pos_src  = (const float*)d_in[4];
    const float* pos_tgt  = (const float*)d_in[5];
    const int*   isrc     = (const int*)d_in[6];
    // d_in[7] = interp_target: structurally repeat(arange(N_TGT), K) -- unused
    const float* W1_mv    = (const float*)d_in[8];
    const float* W2_mv    = (const float*)d_in[9];
    const float* W1_s     = (const float*)d_in[10];
    const float* b1_s     = (const float*)d_in[11];
    const float* W2_s     = (const float*)d_in[12];
    const float* b2_s     = (const float*)d_in[13];
    float* out = (float*)d_out;
    float* ws  = (float*)d_ws;

    size_t need_ws_bytes = PROJ_OFFSET * sizeof(float) + (size_t)N_SRC * 256 * sizeof(__half);
    if (ws_size >= need_ws_bytes) {
        hipLaunchKernelGGL(kA_preproject, dim3(512), dim3(256), 0, stream,
                           mv_src, W1_mv, W2_mv, ws);
        hipLaunchKernelGGL(kB_mv, dim3(2048), dim3(256), 0, stream,
                           ws, mv_skip, pos_src, pos_tgt, isrc, out);
    } else {
        hipLaunchKernelGGL(kBf_mv, dim3(2048), dim3(256), 0, stream,
                           mv_src, mv_skip, pos_src, pos_tgt, isrc, W1_mv, W2_mv, out);
    }
    hipLaunchKernelGGL(kC_scalar, dim3(N_TGT / 64), dim3(256), 0, stream,
                       sc_src, sc_skip, pos_src, pos_tgt, isrc,
                       W1_s, b1_s, W2_s, b2_s, out);
}

// Round 6
// 201.021 us; speedup vs baseline: 1.0787x; 1.0707x over previous
//
#include <hip/hip_runtime.h>
#include <hip/hip_fp16.h>

#define N_SRC 16384
#define N_TGT 65536
#define KNN 8
#define CMV 16
#define CSKIP 2
#define SSC 32
#define HID 64
#define MVD 16

#define OUT_MV_ELEMS (N_TGT * CMV * MVD)   // 16777216 floats
#define PROJ_OFFSET 512                    // floats: skip Weff rows live at ws[0..31]
// fp16 proj table at ws + PROJ_OFFSET: N_SRC x 256 halves (512 B/row, 8 MB)
#define WN_OFFSET (PROJ_OFFSET + (N_SRC * 256 / 2))   // floats; wn[E] normalized IDW weights (2 MB)

typedef float vf4 __attribute__((ext_vector_type(4)));

__device__ __forceinline__ float4 nt_load4(const float* p) {
    vf4 v = __builtin_nontemporal_load((const vf4*)p);
    return make_float4(v.x, v.y, v.z, v.w);
}
__device__ __forceinline__ void nt_store4(float* p, float4 o) {
    vf4 v; v.x = o.x; v.y = o.y; v.z = o.z; v.w = o.w;
    __builtin_nontemporal_store(v, (vf4*)p);
}

__device__ __forceinline__ float gelu_tanh(float x) {
    const float k0 = 0.7978845608028654f;  // sqrt(2/pi)
    const float k1 = 0.044715f;
    float yy = k0 * (x + k1 * x * x * x);
    return 0.5f * x * (1.0f + tanhf(yy));
}

// ---------------------------------------------------------------------------
// Kernel A: (1) per-edge normalized IDW weights -> wn[E] (one thread/target,
// scatter latency absorbed by 131K parallel threads); (2) mv_proj fp16 table
// mv_proj[s][d][i] = sum_c mv_src[s][c][i] * W_eff[c][d], W_eff = W1_mv@W2_mv
// (mv path fully linear).  Block 0 writes skip rows of W_eff to ws[0..31].
// ---------------------------------------------------------------------------
__global__ __launch_bounds__(256) void kA_preproject(
        const float* __restrict__ mv_src,
        const float* __restrict__ pos_src,
        const float* __restrict__ pos_tgt,
        const int*   __restrict__ isrc,
        const float* __restrict__ W1_mv,
        const float* __restrict__ W2_mv,
        float* __restrict__ ws) {
    __shared__ float sWeff[CMV][MVD];
    int tid = threadIdx.x;
    {
        int c = tid >> 4, d = tid & 15;
        float a = 0.f;
        #pragma unroll 8
        for (int h = 0; h < HID; ++h)
            a = fmaf(W1_mv[c * HID + h], W2_mv[h * MVD + d], a);
        sWeff[c][d] = a;
    }
    if (blockIdx.x == 0 && tid < 32) {
        int j = tid >> 4, d = tid & 15;
        float a = 0.f;
        #pragma unroll 8
        for (int h = 0; h < HID; ++h)
            a = fmaf(W1_mv[(CMV + j) * HID + h], W2_mv[h * MVD + d], a);
        ws[j * MVD + d] = a;
    }

    // --- phase W: IDW weights, one thread per target ---
    int gid = blockIdx.x * 256 + tid;
    if (gid < N_TGT) {
        int t = gid;
        float ptx = pos_tgt[t * 3 + 0], pty = pos_tgt[t * 3 + 1], ptz = pos_tgt[t * 3 + 2];
        int4 e0 = *(const int4*)(isrc + t * KNN);
        int4 e1 = *(const int4*)(isrc + t * KNN + 4);
        int sk[KNN] = {e0.x, e0.y, e0.z, e0.w, e1.x, e1.y, e1.z, e1.w};
        float wk[KNN];
        float den = 0.f;
        #pragma unroll
        for (int k = 0; k < KNN; ++k) {
            int s = sk[k];
            float dx = pos_src[s * 3 + 0] - ptx;
            float dy = pos_src[s * 3 + 1] - pty;
            float dz = pos_src[s * 3 + 2] - ptz;
            float d2 = fmaxf(dx * dx + dy * dy + dz * dz, 1e-16f);
            wk[k] = 1.0f / d2;
            den += wk[k];
        }
        float invd = 1.0f / den;
        float* wn = ws + WN_OFFSET;
        float4 a = make_float4(wk[0] * invd, wk[1] * invd, wk[2] * invd, wk[3] * invd);
        float4 b = make_float4(wk[4] * invd, wk[5] * invd, wk[6] * invd, wk[7] * invd);
        *(float4*)(wn + (size_t)t * 8)     = a;
        *(float4*)(wn + (size_t)t * 8 + 4) = b;
    }
    __syncthreads();

    // --- phase P: projection table ---
    int lane = tid & 63;
    int d = lane >> 2, q = lane & 3;
    float wcol[CMV];
    #pragma unroll
    for (int c = 0; c < CMV; ++c) wcol[c] = sWeff[c][d];

    __half* proj = (__half*)(ws + PROJ_OFFSET);
    int wid = (int)((blockIdx.x * blockDim.x + tid) >> 6);
    int nw  = (int)((gridDim.x * blockDim.x) >> 6);
    for (int s = wid; s < N_SRC; s += nw) {
        const float* row = mv_src + (size_t)s * 256;
        float4 o = make_float4(0.f, 0.f, 0.f, 0.f);
        #pragma unroll
        for (int c = 0; c < CMV; ++c) {
            float4 v = *(const float4*)(row + c * 16 + q * 4);
            o.x = fmaf(v.x, wcol[c], o.x);
            o.y = fmaf(v.y, wcol[c], o.y);
            o.z = fmaf(v.z, wcol[c], o.z);
            o.w = fmaf(v.w, wcol[c], o.w);
        }
        union { __half2 h[2]; uint2 u; } P;
        P.h[0] = __floats2half2_rn(o.x, o.y);
        P.h[1] = __floats2half2_rn(o.z, o.w);
        *(uint2*)(proj + (size_t)s * 256 + lane * 4) = P.u;
    }
}

// ---------------------------------------------------------------------------
// Kernel B: mv output, 2 targets per wave (32768 waves).  Preamble is two
// coalesced 64B loads (isrc + precomputed wn); then 16 independent gathers,
// one wait, consume, NT-store, retire.  MLP comes from wave count (TLP), not
// per-wave pipelining -- no regalloc fight, no scattered pos reads.
// ---------------------------------------------------------------------------
__global__ __launch_bounds__(256, 6) void kB_mv(
        const float* __restrict__ ws,
        const float* __restrict__ mv_skip,
        const int*   __restrict__ isrc,
        float* __restrict__ out) {
    int tid = threadIdx.x;
    int lane = tid & 63;
    int dd = lane >> 2, q = lane & 3;
    float wsk0 = ws[dd], wsk1 = ws[MVD + dd];
    const __half* proj = (const __half*)(ws + PROJ_OFFSET);
    const float*  wn   = ws + WN_OFFSET;

    int wid = (int)((blockIdx.x * blockDim.x + tid) >> 6);  // 0..32767
    int t0 = wid * 2;

    // preamble: 16 edges (2 targets) via coalesced 64B loads
    int   src2 = 0; float wn2 = 0.f;
    if (lane < 16) {
        src2 = isrc[(size_t)t0 * KNN + lane];
        wn2  = wn[(size_t)t0 * KNN + lane];
    }

    // skip-stream loads (issue early, consumed in epilogue)
    float4 u0A = nt_load4(mv_skip + (size_t)t0 * 32 + q * 4);
    float4 u1A = nt_load4(mv_skip + (size_t)t0 * 32 + 16 + q * 4);
    float4 u0B = nt_load4(mv_skip + (size_t)(t0 + 1) * 32 + q * 4);
    float4 u1B = nt_load4(mv_skip + (size_t)(t0 + 1) * 32 + 16 + q * 4);

    // 16 independent gathers (512B coalesced per edge row)
    uint2 g[16];
    #pragma unroll
    for (int k = 0; k < 16; ++k) {
        int sk = __builtin_amdgcn_readlane(src2, k);
        g[k] = *(const uint2*)(proj + (size_t)sk * 256 + lane * 4);
    }

    float4 accA = make_float4(0.f, 0.f, 0.f, 0.f);
    float4 accB = make_float4(0.f, 0.f, 0.f, 0.f);
    #pragma unroll
    for (int k = 0; k < KNN; ++k) {
        float wk = __uint_as_float(__builtin_amdgcn_readlane(__float_as_uint(wn2), k));
        union { uint2 u; __half2 h[2]; } P; P.u = g[k];
        float2 lo = __half22float2(P.h[0]);
        float2 hi = __half22float2(P.h[1]);
        accA.x = fmaf(wk, lo.x, accA.x);
        accA.y = fmaf(wk, lo.y, accA.y);
        accA.z = fmaf(wk, hi.x, accA.z);
        accA.w = fmaf(wk, hi.y, accA.w);
    }
    #pragma unroll
    for (int k = 0; k < KNN; ++k) {
        float wk = __uint_as_float(__builtin_amdgcn_readlane(__float_as_uint(wn2), 8 + k));
        union { uint2 u; __half2 h[2]; } P; P.u = g[8 + k];
        float2 lo = __half22float2(P.h[0]);
        float2 hi = __half22float2(P.h[1]);
        accB.x = fmaf(wk, lo.x, accB.x);
        accB.y = fmaf(wk, lo.y, accB.y);
        accB.z = fmaf(wk, hi.x, accB.z);
        accB.w = fmaf(wk, hi.y, accB.w);
    }

    {
        float4 o;
        o.x = accA.x + fmaf(wsk0, u0A.x, wsk1 * u1A.x);
        o.y = accA.y + fmaf(wsk0, u0A.y, wsk1 * u1A.y);
        o.z = accA.z + fmaf(wsk0, u0A.z, wsk1 * u1A.z);
        o.w = accA.w + fmaf(wsk0, u0A.w, wsk1 * u1A.w);
        nt_store4(out + (size_t)t0 * 256 + lane * 4, o);
    }
    {
        float4 o;
        o.x = accB.x + fmaf(wsk0, u0B.x, wsk1 * u1B.x);
        o.y = accB.y + fmaf(wsk0, u0B.y, wsk1 * u1B.y);
        o.z = accB.z + fmaf(wsk0, u0B.z, wsk1 * u1B.z);
        o.w = accB.w + fmaf(wsk0, u0B.w, wsk1 * u1B.w);
        nt_store4(out + (size_t)(t0 + 1) * 256 + lane * 4, o);
    }
}

// ---------------------------------------------------------------------------
// Fallback (ws too small): f32 mv gather + W_eff via LDS stage (unchanged).
// ---------------------------------------------------------------------------
__global__ __launch_bounds__(256) void kBf_mv(
        const float* __restrict__ mv_src,
        const float* __restrict__ mv_skip,
        const float* __restrict__ pos_src,
        const float* __restrict__ pos_tgt,
        const int*   __restrict__ isrc,
        const float* __restrict__ W1_mv,
        const float* __restrict__ W2_mv,
        float* __restrict__ out) {
    __shared__ float sWeff[CMV + CSKIP][MVD];
    __shared__ float stage[4][256];
    int tid = threadIdx.x;
    for (int e = tid; e < (CMV + CSKIP) * MVD; e += 256) {
        int c = e >> 4, d = e & 15;
        float a = 0.f;
        #pragma unroll 8
        for (int h = 0; h < HID; ++h)
            a = fmaf(W1_mv[c * HID + h], W2_mv[h * MVD + d], a);
        sWeff[c][d] = a;
    }
    __syncthreads();

    int lane = tid & 63, wv = tid >> 6;
    int d = lane >> 2, q = lane & 3;
    float wcol[CMV + CSKIP];
    #pragma unroll
    for (int c = 0; c < CMV + CSKIP; ++c) wcol[c] = sWeff[c][d];

    int wid = (int)((blockIdx.x * blockDim.x + tid) >> 6);
    int nw  = (int)((gridDim.x * blockDim.x) >> 6);
    for (int t = wid; t < N_TGT; t += nw) {
        float w = 0.f; int src = 0;
        if (lane < KNN) {
            src = isrc[t * KNN + lane];
            float dx = pos_src[src * 3 + 0] - pos_tgt[t * 3 + 0];
            float dy = pos_src[src * 3 + 1] - pos_tgt[t * 3 + 1];
            float dz = pos_src[src * 3 + 2] - pos_tgt[t * 3 + 2];
            float d2 = fmaxf(dx * dx + dy * dy + dz * dz, 1e-16f);
            w = 1.0f / d2;
        }
        float denom = w;
        denom += __shfl_xor(denom, 1);
        denom += __shfl_xor(denom, 2);
        denom += __shfl_xor(denom, 4);
        denom = __shfl(denom, 0);
        float invd = 1.0f / denom;

        float4 acc = make_float4(0.f, 0.f, 0.f, 0.f);
        #pragma unroll
        for (int k = 0; k < KNN; ++k) {
            int   sk = __builtin_amdgcn_readlane(src, k);
            float wk = __uint_as_float(__builtin_amdgcn_readlane(__float_as_uint(w), k));
            float4 v = *(const float4*)(mv_src + (size_t)sk * 256 + lane * 4);
            acc.x = fmaf(wk, v.x, acc.x);
            acc.y = fmaf(wk, v.y, acc.y);
            acc.z = fmaf(wk, v.z, acc.z);
            acc.w = fmaf(wk, v.w, acc.w);
        }
        asm volatile("" ::: "memory");
        *(float4*)&stage[wv][lane * 4] = acc;
        asm volatile("s_waitcnt lgkmcnt(0)" ::: "memory");
        __builtin_amdgcn_sched_barrier(0);

        float4 o = make_float4(0.f, 0.f, 0.f, 0.f);
        #pragma unroll
        for (int c = 0; c < CMV; ++c) {
            float4 v = *(const float4*)&stage[wv][c * 16 + q * 4];
            o.x = fmaf(v.x, wcol[c], o.x);
            o.y = fmaf(v.y, wcol[c], o.y);
            o.z = fmaf(v.z, wcol[c], o.z);
            o.w = fmaf(v.w, wcol[c], o.w);
        }
        const float4 u0 = *(const float4*)(mv_skip + (size_t)t * 32 + q * 4);
        const float4 u1 = *(const float4*)(mv_skip + (size_t)t * 32 + 16 + q * 4);
        float4 r;
        r.x = fmaf(o.x, invd, fmaf(wcol[16], u0.x, wcol[17] * u1.x));
        r.y = fmaf(o.y, invd, fmaf(wcol[16], u0.y, wcol[17] * u1.y));
        r.z = fmaf(o.z, invd, fmaf(wcol[16], u0.z, wcol[17] * u1.z));
        r.w = fmaf(o.w, invd, fmaf(wcol[16], u0.w, wcol[17] * u1.w));
        *(float4*)(out + (size_t)t * 256 + lane * 4) = r;
    }
}

// ---------------------------------------------------------------------------
// Kernel C: scalar path.  Phase 1 reads precomputed wn when available
// (coalesced 2KB isrc + 2KB wn per block) instead of scattered pos gathers.
// ---------------------------------------------------------------------------
__global__ __launch_bounds__(256) void kC_scalar(
        const float* __restrict__ sc_src,
        const float* __restrict__ sc_skip,
        const float* __restrict__ pos_src,
        const float* __restrict__ pos_tgt,
        const int*   __restrict__ isrc,
        const float* __restrict__ wn,        // may be null (fallback)
        const float* __restrict__ W1_s,
        const float* __restrict__ b1_s,
        const float* __restrict__ W2_s,
        const float* __restrict__ b2_s,
        float* __restrict__ out) {
    __shared__ float sW1[HID * HID];
    __shared__ float sW2T[SSC][68];
    __shared__ float sXT[HID][68];
    __shared__ float sH[64][68];
    __shared__ float swgt[64][9];
    __shared__ int   ssrcl[64][9];
    __shared__ float sb1[HID], sb2[SSC];

    int tid = threadIdx.x;
    #pragma unroll
    for (int r = 0; r < 4; ++r) {
        float4 v = *(const float4*)(W1_s + (r * 256 + tid) * 4);
        *(float4*)&sW1[(r * 256 + tid) * 4] = v;
    }
    for (int e = tid; e < HID * SSC; e += 256) {
        int h = e >> 5, s = e & 31;
        sW2T[s][h] = W2_s[e];
    }
    if (tid < HID) sb1[tid] = b1_s[tid];
    else if (tid < HID + SSC) sb2[tid - HID] = b2_s[tid - HID];

    int t0 = blockIdx.x * 64;
    if (tid < 64) {
        int t = t0 + tid;
        int4 e0 = *(const int4*)(isrc + t * KNN);
        int4 e1 = *(const int4*)(isrc + t * KNN + 4);
        int sk[KNN] = {e0.x, e0.y, e0.z, e0.w, e1.x, e1.y, e1.z, e1.w};
        float wkn[KNN];
        if (wn) {
            float4 a = *(const float4*)(wn + (size_t)t * 8);
            float4 b = *(const float4*)(wn + (size_t)t * 8 + 4);
            wkn[0] = a.x; wkn[1] = a.y; wkn[2] = a.z; wkn[3] = a.w;
            wkn[4] = b.x; wkn[5] = b.y; wkn[6] = b.z; wkn[7] = b.w;
        } else {
            float ptx = pos_tgt[t * 3 + 0], pty = pos_tgt[t * 3 + 1], ptz = pos_tgt[t * 3 + 2];
            float den = 0.f;
            #pragma unroll
            for (int k = 0; k < KNN; ++k) {
                int s = sk[k];
                float dx = pos_src[s * 3 + 0] - ptx;
                float dy = pos_src[s * 3 + 1] - pty;
                float dz = pos_src[s * 3 + 2] - ptz;
                float d2 = fmaxf(dx * dx + dy * dy + dz * dz, 1e-16f);
                wkn[k] = 1.0f / d2;
                den += wkn[k];
            }
            float invd = 1.0f / den;
            #pragma unroll
            for (int k = 0; k < KNN; ++k) wkn[k] *= invd;
        }
        #pragma unroll
        for (int k = 0; k < KNN; ++k) {
            swgt[tid][k]  = wkn[k];
            ssrcl[tid][k] = sk[k];
        }
    }
    __syncthreads();

    {
        int wv = tid >> 6, lane = tid & 63;
        int k = lane >> 3;
        int m = lane & 7;
        for (int i = 0; i < 16; i += 4) {
            int tb = wv * 16 + i;
            float4 v[4]; float wn4[4];
            #pragma unroll
            for (int j = 0; j < 4; ++j) {
                int tl = tb + j;
                wn4[j] = swgt[tl][k];
                int sk = ssrcl[tl][k];
                v[j] = *(const float4*)(sc_src + (size_t)sk * SSC + m * 4);
            }
            float4 u;
            if (lane < 32)
                u = *(const float4*)(sc_skip + (size_t)(t0 + tb + k) * SSC + m * 4);
            #pragma unroll
            for (int j = 0; j < 4; ++j) {
                float4 a = v[j]; float wnj = wn4[j];
                a.x *= wnj; a.y *= wnj; a.z *= wnj; a.w *= wnj;
                #pragma unroll
                for (int sft = 8; sft <= 32; sft <<= 1) {
                    a.x += __shfl_xor(a.x, sft);
                    a.y += __shfl_xor(a.y, sft);
                    a.z += __shfl_xor(a.z, sft);
                    a.w += __shfl_xor(a.w, sft);
                }
                if (lane < 8) {
                    sXT[4 * lane + 0][tb + j] = a.x;
                    sXT[4 * lane + 1][tb + j] = a.y;
                    sXT[4 * lane + 2][tb + j] = a.z;
                    sXT[4 * lane + 3][tb + j] = a.w;
                }
            }
            if (lane < 32) {
                sXT[SSC + 4 * m + 0][tb + k] = u.x;
                sXT[SSC + 4 * m + 1][tb + k] = u.y;
                sXT[SSC + 4 * m + 2][tb + k] = u.z;
                sXT[SSC + 4 * m + 3][tb + k] = u.w;
            }
        }
    }
    __syncthreads();

    int wv = tid >> 6;
    int lane = tid & 63;
    int tr4 = lane >> 4;
    int hc  = lane & 15;
    int tbase = wv * 16 + tr4 * 4;
    float acc[4][4];
    #pragma unroll
    for (int i = 0; i < 4; ++i)
        #pragma unroll
        for (int j = 0; j < 4; ++j) acc[i][j] = 0.f;

    #pragma unroll 2
    for (int c = 0; c < HID; ++c) {
        float4 xv = *(const float4*)&sXT[c][tbase];
        float4 wv4 = *(const float4*)&sW1[c * HID + hc * 4];
        acc[0][0] = fmaf(xv.x, wv4.x, acc[0][0]);
        acc[0][1] = fmaf(xv.x, wv4.y, acc[0][1]);
        acc[0][2] = fmaf(xv.x, wv4.z, acc[0][2]);
        acc[0][3] = fmaf(xv.x, wv4.w, acc[0][3]);
        acc[1][0] = fmaf(xv.y, wv4.x, acc[1][0]);
        acc[1][1] = fmaf(xv.y, wv4.y, acc[1][1]);
        acc[1][2] = fmaf(xv.y, wv4.z, acc[1][2]);
        acc[1][3] = fmaf(xv.y, wv4.w, acc[1][3]);
        acc[2][0] = fmaf(xv.z, wv4.x, acc[2][0]);
        acc[2][1] = fmaf(xv.z, wv4.y, acc[2][1]);
        acc[2][2] = fmaf(xv.z, wv4.z, acc[2][2]);
        acc[2][3] = fmaf(xv.z, wv4.w, acc[2][3]);
        acc[3][0] = fmaf(xv.w, wv4.x, acc[3][0]);
        acc[3][1] = fmaf(xv.w, wv4.y, acc[3][1]);
        acc[3][2] = fmaf(xv.w, wv4.z, acc[3][2]);
        acc[3][3] = fmaf(xv.w, wv4.w, acc[3][3]);
    }
    {
        float b0 = sb1[hc * 4 + 0], b1 = sb1[hc * 4 + 1];
        float b2 = sb1[hc * 4 + 2], b3 = sb1[hc * 4 + 3];
        #pragma unroll
        for (int i = 0; i < 4; ++i) {
            float4 hv;
            hv.x = gelu_tanh(acc[i][0] + b0);
            hv.y = gelu_tanh(acc[i][1] + b1);
            hv.z = gelu_tanh(acc[i][2] + b2);
            hv.w = gelu_tanh(acc[i][3] + b3);
            *(float4*)&sH[tbase + i][hc * 4] = hv;
        }
    }
    __syncthreads();

    int sc16 = lane & 15;
    float acc2[4][2];
    #pragma unroll
    for (int i = 0; i < 4; ++i) { acc2[i][0] = 0.f; acc2[i][1] = 0.f; }
    #pragma unroll 2
    for (int hh = 0; hh < 16; ++hh) {
        float4 wa = *(const float4*)&sW2T[sc16 * 2 + 0][hh * 4];
        float4 wb = *(const float4*)&sW2T[sc16 * 2 + 1][hh * 4];
        #pragma unroll
        for (int i = 0; i < 4; ++i) {
            float4 hv = *(const float4*)&sH[tbase + i][hh * 4];
            acc2[i][0] = fmaf(hv.x, wa.x, acc2[i][0]);
            acc2[i][0] = fmaf(hv.y, wa.y, acc2[i][0]);
            acc2[i][0] = fmaf(hv.z, wa.z, acc2[i][0]);
            acc2[i][0] = fmaf(hv.w, wa.w, acc2[i][0]);
            acc2[i][1] = fmaf(hv.x, wb.x, acc2[i][1]);
            acc2[i][1] = fmaf(hv.y, wb.y, acc2[i][1]);
            acc2[i][1] = fmaf(hv.z, wb.z, acc2[i][1]);
            acc2[i][1] = fmaf(hv.w, wb.w, acc2[i][1]);
        }
    }
    float* osc = out + OUT_MV_ELEMS;
    float bb0 = sb2[sc16 * 2 + 0], bb1 = sb2[sc16 * 2 + 1];
    #pragma unroll
    for (int i = 0; i < 4; ++i) {
        int t = t0 + tbase + i;
        float2 r = make_float2(acc2[i][0] + bb0, acc2[i][1] + bb1);
        *(float2*)&osc[(size_t)t * SSC + sc16 * 2] = r;
    }
}

// ---------------------------------------------------------------------------
extern "C" void kernel_launch(void* const* d_in, const int* in_sizes, int n_in,
                              void* d_out, int out_size, void* d_ws, size_t ws_size,
                              hipStream_t stream) {
    const float* mv_src   = (const float*)d_in[0];
    const float* mv_skip  = (const float*)d_in[1];
    const float* sc_src   = (const float*)d_in[2];
    const float* sc_skip  = (const float*)d_in[3];
    const float* pos_src  = (const float*)d_in[4];
    const float* pos_tgt  = (const float*)d_in[5];
    const int*   isrc     = (const int*)d_in[6];
    // d_in[7] = interp_target: structurally repeat(arange(N_TGT), K) -- unused
    const float* W1_mv    = (const float*)d_in[8];
    const float* W2_mv    = (const float*)d_in[9];
    const float* W1_s     = (const float*)d_in[10];
    const float* b1_s     = (const float*)d_in[11];
    const float* W2_s     = (const float*)d_in[12];
    const float* b2_s     = (const float*)d_in[13];
    float* out = (float*)d_out;
    float* ws  = (float*)d_ws;

    size_t need_ws_bytes = (size_t)(WN_OFFSET + (size_t)N_TGT * KNN) * sizeof(float);
    if (ws_size >= need_ws_bytes) {
        hipLaunchKernelGGL(kA_preproject, dim3(512), dim3(256), 0, stream,
                           mv_src, pos_src, pos_tgt, isrc, W1_mv, W2_mv, ws);
        hipLaunchKernelGGL(kB_mv, dim3(8192), dim3(256), 0, stream,
                           ws, mv_skip, isrc, out);
        hipLaunchKernelGGL(kC_scalar, dim3(N_TGT / 64), dim3(256), 0, stream,
                           sc_src, sc_skip, pos_src, pos_tgt, isrc, ws + WN_OFFSET,
                           W1_s, b1_s, W2_s, b2_s, out);
    } else {
        hipLaunchKernelGGL(kBf_mv, dim3(2048), dim3(256), 0, stream,
                           mv_src, mv_skip, pos_src, pos_tgt, isrc, W1_mv, W2_mv, out);
        hipLaunchKernelGGL(kC_scalar, dim3(N_TGT / 64), dim3(256), 0, stream,
                           sc_src, sc_skip, pos_src, pos_tgt, isrc, (const float*)nullptr,
                           W1_s, b1_s, W2_s, b2_s, out);
    }
}

// Round 7
// 199.627 us; speedup vs baseline: 1.0862x; 1.0070x over previous
//
#include <hip/hip_runtime.h>
#include <hip/hip_fp16.h>

#define N_SRC 16384
#define N_TGT 65536
#define KNN 8
#define CMV 16
#define CSKIP 2
#define SSC 32
#define HID 64
#define MVD 16

#define OUT_MV_ELEMS (N_TGT * CMV * MVD)   // 16777216 floats
#define PROJ_OFFSET 512                    // floats: skip Weff rows live at ws[0..31]
// fp16 proj table at ws + PROJ_OFFSET: N_SRC x 256 halves (512 B/row, 8 MB)
#define WN_OFFSET (PROJ_OFFSET + (N_SRC * 256 / 2))   // floats; wn[E] normalized IDW weights (2 MB)

typedef float vf4 __attribute__((ext_vector_type(4)));

__device__ __forceinline__ float4 nt_load4(const float* p) {
    vf4 v = __builtin_nontemporal_load((const vf4*)p);
    return make_float4(v.x, v.y, v.z, v.w);
}
__device__ __forceinline__ void nt_store4(float* p, float4 o) {
    vf4 v; v.x = o.x; v.y = o.y; v.z = o.z; v.w = o.w;
    __builtin_nontemporal_store(v, (vf4*)p);
}

__device__ __forceinline__ float gelu_tanh(float x) {
    const float k0 = 0.7978845608028654f;  // sqrt(2/pi)
    const float k1 = 0.044715f;
    float yy = k0 * (x + k1 * x * x * x);
    return 0.5f * x * (1.0f + tanhf(yy));
}

// ---------------------------------------------------------------------------
// Kernel A: (1) per-edge normalized IDW weights -> wn[E]; (2) fp16 mv_proj
// table  mv_proj[s][d][i] = sum_c mv_src[s][c][i] * W_eff[c][d],
// W_eff = W1_mv @ W2_mv (mv path fully linear).  Block 0 writes skip rows
// of W_eff to ws[0..31].
// ---------------------------------------------------------------------------
__global__ __launch_bounds__(256) void kA_preproject(
        const float* __restrict__ mv_src,
        const float* __restrict__ pos_src,
        const float* __restrict__ pos_tgt,
        const int*   __restrict__ isrc,
        const float* __restrict__ W1_mv,
        const float* __restrict__ W2_mv,
        float* __restrict__ ws) {
    __shared__ float sWeff[CMV][MVD];
    int tid = threadIdx.x;
    {
        int c = tid >> 4, d = tid & 15;
        float a = 0.f;
        #pragma unroll 8
        for (int h = 0; h < HID; ++h)
            a = fmaf(W1_mv[c * HID + h], W2_mv[h * MVD + d], a);
        sWeff[c][d] = a;
    }
    if (blockIdx.x == 0 && tid < 32) {
        int j = tid >> 4, d = tid & 15;
        float a = 0.f;
        #pragma unroll 8
        for (int h = 0; h < HID; ++h)
            a = fmaf(W1_mv[(CMV + j) * HID + h], W2_mv[h * MVD + d], a);
        ws[j * MVD + d] = a;
    }

    // --- phase W: IDW weights, one thread per target ---
    int gid = blockIdx.x * 256 + tid;
    if (gid < N_TGT) {
        int t = gid;
        float ptx = pos_tgt[t * 3 + 0], pty = pos_tgt[t * 3 + 1], ptz = pos_tgt[t * 3 + 2];
        int4 e0 = *(const int4*)(isrc + t * KNN);
        int4 e1 = *(const int4*)(isrc + t * KNN + 4);
        int sk[KNN] = {e0.x, e0.y, e0.z, e0.w, e1.x, e1.y, e1.z, e1.w};
        float wk[KNN];
        float den = 0.f;
        #pragma unroll
        for (int k = 0; k < KNN; ++k) {
            int s = sk[k];
            float dx = pos_src[s * 3 + 0] - ptx;
            float dy = pos_src[s * 3 + 1] - pty;
            float dz = pos_src[s * 3 + 2] - ptz;
            float d2 = fmaxf(dx * dx + dy * dy + dz * dz, 1e-16f);
            wk[k] = 1.0f / d2;
            den += wk[k];
        }
        float invd = 1.0f / den;
        float* wn = ws + WN_OFFSET;
        float4 a = make_float4(wk[0] * invd, wk[1] * invd, wk[2] * invd, wk[3] * invd);
        float4 b = make_float4(wk[4] * invd, wk[5] * invd, wk[6] * invd, wk[7] * invd);
        *(float4*)(wn + (size_t)t * 8)     = a;
        *(float4*)(wn + (size_t)t * 8 + 4) = b;
    }
    __syncthreads();

    // --- phase P: projection table ---
    int lane = tid & 63;
    int d = lane >> 2, q = lane & 3;
    float wcol[CMV];
    #pragma unroll
    for (int c = 0; c < CMV; ++c) wcol[c] = sWeff[c][d];

    __half* proj = (__half*)(ws + PROJ_OFFSET);
    int wid = (int)((blockIdx.x * blockDim.x + tid) >> 6);
    int nw  = (int)((gridDim.x * blockDim.x) >> 6);
    for (int s = wid; s < N_SRC; s += nw) {
        const float* row = mv_src + (size_t)s * 256;
        float4 o = make_float4(0.f, 0.f, 0.f, 0.f);
        #pragma unroll
        for (int c = 0; c < CMV; ++c) {
            float4 v = *(const float4*)(row + c * 16 + q * 4);
            o.x = fmaf(v.x, wcol[c], o.x);
            o.y = fmaf(v.y, wcol[c], o.y);
            o.z = fmaf(v.z, wcol[c], o.z);
            o.w = fmaf(v.w, wcol[c], o.w);
        }
        union { __half2 h[2]; uint2 u; } P;
        P.h[0] = __floats2half2_rn(o.x, o.y);
        P.h[1] = __floats2half2_rn(o.z, o.w);
        *(uint2*)(proj + (size_t)s * 256 + lane * 4) = P.u;
    }
}

// ---------------------------------------------------------------------------
// Fused kernel: block-level fusion of the mv gather path (8192 block-slots,
// exact round-6 kB code: 2 targets/wave, TLP-driven) and the scalar MLP path
// (2048 block-slots, 32 targets each).  bid%5==4 -> scalar.  The paths are
// independent (both depend only on kA) -- block fusion lets the scalar
// blocks' VALU/LDS work execute in the issue slots the latency-bound mv
// blocks leave idle (kB VALUBusy was 26%).  Scalar LDS kept to ~17KB (W1 and
// biases come straight from global through L1) so mv occupancy stays
// VGPR-capped, not LDS-capped.
// ---------------------------------------------------------------------------
__global__ __launch_bounds__(256, 6) void kFused(
        const float* __restrict__ ws,
        const float* __restrict__ mv_skip,
        const float* __restrict__ sc_src,
        const float* __restrict__ sc_skip,
        const int*   __restrict__ isrc,
        const float* __restrict__ W1_s,
        const float* __restrict__ b1_s,
        const float* __restrict__ W2_s,
        const float* __restrict__ b2_s,
        float* __restrict__ out) {
    __shared__ float sW2T[SSC][HID + 4];   // [s][h] padded
    __shared__ float sX[4][8][HID];        // per-wave cat-X, reused as H

    int tid = threadIdx.x;
    int bid = blockIdx.x;
    int lane = tid & 63, wv = tid >> 6;
    bool is_sc = (bid % 5) == 4;

    if (!is_sc) {
        // ================= mv path (round-6 kB, unchanged) =================
        int dd = lane >> 2, q = lane & 3;
        float wsk0 = ws[dd], wsk1 = ws[MVD + dd];
        const __half* proj = (const __half*)(ws + PROJ_OFFSET);
        const float*  wn   = ws + WN_OFFSET;

        int mvb = (bid / 5) * 4 + (bid % 5);          // 0..8191
        int wid = mvb * 4 + wv;                        // 0..32767
        int t0 = wid * 2;

        int   src2 = 0; float wn2 = 0.f;
        if (lane < 16) {
            src2 = isrc[(size_t)t0 * KNN + lane];
            wn2  = wn[(size_t)t0 * KNN + lane];
        }

        float4 u0A = nt_load4(mv_skip + (size_t)t0 * 32 + q * 4);
        float4 u1A = nt_load4(mv_skip + (size_t)t0 * 32 + 16 + q * 4);
        float4 u0B = nt_load4(mv_skip + (size_t)(t0 + 1) * 32 + q * 4);
        float4 u1B = nt_load4(mv_skip + (size_t)(t0 + 1) * 32 + 16 + q * 4);

        uint2 g[16];
        #pragma unroll
        for (int k = 0; k < 16; ++k) {
            int sk = __builtin_amdgcn_readlane(src2, k);
            g[k] = *(const uint2*)(proj + (size_t)sk * 256 + lane * 4);
        }

        float4 accA = make_float4(0.f, 0.f, 0.f, 0.f);
        float4 accB = make_float4(0.f, 0.f, 0.f, 0.f);
        #pragma unroll
        for (int k = 0; k < KNN; ++k) {
            float wk = __uint_as_float(__builtin_amdgcn_readlane(__float_as_uint(wn2), k));
            union { uint2 u; __half2 h[2]; } P; P.u = g[k];
            float2 lo = __half22float2(P.h[0]);
            float2 hi = __half22float2(P.h[1]);
            accA.x = fmaf(wk, lo.x, accA.x);
            accA.y = fmaf(wk, lo.y, accA.y);
            accA.z = fmaf(wk, hi.x, accA.z);
            accA.w = fmaf(wk, hi.y, accA.w);
        }
        #pragma unroll
        for (int k = 0; k < KNN; ++k) {
            float wk = __uint_as_float(__builtin_amdgcn_readlane(__float_as_uint(wn2), 8 + k));
            union { uint2 u; __half2 h[2]; } P; P.u = g[8 + k];
            float2 lo = __half22float2(P.h[0]);
            float2 hi = __half22float2(P.h[1]);
            accB.x = fmaf(wk, lo.x, accB.x);
            accB.y = fmaf(wk, lo.y, accB.y);
            accB.z = fmaf(wk, hi.x, accB.z);
            accB.w = fmaf(wk, hi.y, accB.w);
        }

        {
            float4 o;
            o.x = accA.x + fmaf(wsk0, u0A.x, wsk1 * u1A.x);
            o.y = accA.y + fmaf(wsk0, u0A.y, wsk1 * u1A.y);
            o.z = accA.z + fmaf(wsk0, u0A.z, wsk1 * u1A.z);
            o.w = accA.w + fmaf(wsk0, u0A.w, wsk1 * u1A.w);
            nt_store4(out + (size_t)t0 * 256 + lane * 4, o);
        }
        {
            float4 o;
            o.x = accB.x + fmaf(wsk0, u0B.x, wsk1 * u1B.x);
            o.y = accB.y + fmaf(wsk0, u0B.y, wsk1 * u1B.y);
            o.z = accB.z + fmaf(wsk0, u0B.z, wsk1 * u1B.z);
            o.w = accB.w + fmaf(wsk0, u0B.w, wsk1 * u1B.w);
            nt_store4(out + (size_t)(t0 + 1) * 256 + lane * 4, o);
        }
        return;
    }

    // ===================== scalar path (32 targets/block) =====================
    // stage W2^T (block-uniform branch -> barrier is safe)
    for (int e = tid; e < HID * SSC; e += 256) {
        int h = e >> 5, s = e & 31;
        sW2T[s][h] = W2_s[e];
    }
    __syncthreads();

    const float* wn = ws + WN_OFFSET;
    int sbid = bid / 5;                         // 0..2047
    int t0 = (sbid * 4 + wv) * 8;               // 8 targets per wave

    // 64 edges for this wave's 8 targets, coalesced
    int   se = isrc[(size_t)t0 * KNN + lane];
    float we = wn[(size_t)t0 * KNN + lane];

    int kk = lane >> 3, mm = lane & 7;

    // gather + xor-reduce over edges; lane mm writes chunk mm of target tt
    #pragma unroll
    for (int tt = 0; tt < 8; ++tt) {
        int   s = __shfl(se, tt * 8 + kk);
        float w = __shfl(we, tt * 8 + kk);
        float4 v = *(const float4*)(sc_src + (size_t)s * SSC + mm * 4);
        v.x *= w; v.y *= w; v.z *= w; v.w *= w;
        #pragma unroll
        for (int sft = 8; sft <= 32; sft <<= 1) {
            v.x += __shfl_xor(v.x, sft);
            v.y += __shfl_xor(v.y, sft);
            v.z += __shfl_xor(v.z, sft);
            v.w += __shfl_xor(v.w, sft);
        }
        if (lane < 8)
            *(float4*)&sX[wv][tt][lane * 4] = v;
    }
    // skip half: 64 lanes = 8 targets x 8 chunks, fully coalesced
    {
        int tt = lane >> 3;
        float4 u = nt_load4(sc_skip + (size_t)(t0 + tt) * SSC + mm * 4);
        *(float4*)&sX[wv][tt][SSC + mm * 4] = u;
    }

    // GEMM1: h = lane; W1 column read straight from global (16KB, L1-hot)
    float acc1[8];
    #pragma unroll
    for (int tt = 0; tt < 8; ++tt) acc1[tt] = 0.f;
    #pragma unroll 4
    for (int c4 = 0; c4 < 16; ++c4) {
        float w0 = W1_s[(c4 * 4 + 0) * HID + lane];
        float w1 = W1_s[(c4 * 4 + 1) * HID + lane];
        float w2 = W1_s[(c4 * 4 + 2) * HID + lane];
        float w3 = W1_s[(c4 * 4 + 3) * HID + lane];
        #pragma unroll
        for (int tt = 0; tt < 8; ++tt) {
            float4 x4 = *(const float4*)&sX[wv][tt][c4 * 4];   // LDS broadcast
            acc1[tt] = fmaf(x4.x, w0, acc1[tt]);
            acc1[tt] = fmaf(x4.y, w1, acc1[tt]);
            acc1[tt] = fmaf(x4.z, w2, acc1[tt]);
            acc1[tt] = fmaf(x4.w, w3, acc1[tt]);
        }
    }
    {
        float bb = b1_s[lane];
        #pragma unroll
        for (int tt = 0; tt < 8; ++tt)
            sX[wv][tt][lane] = gelu_tanh(acc1[tt] + bb);   // X consumed; reuse as H
    }

    // GEMM2: lane = th*32 + s; 4 targets per thread
    {
        int s = lane & 31, th = lane >> 5;
        float acc2[4];
        #pragma unroll
        for (int i = 0; i < 4; ++i) acc2[i] = 0.f;
        #pragma unroll 4
        for (int h4 = 0; h4 < 16; ++h4) {
            float4 w4 = *(const float4*)&sW2T[s][h4 * 4];
            #pragma unroll
            for (int i = 0; i < 4; ++i) {
                float4 x4 = *(const float4*)&sX[wv][th * 4 + i][h4 * 4];
                acc2[i] = fmaf(x4.x, w4.x, acc2[i]);
                acc2[i] = fmaf(x4.y, w4.y, acc2[i]);
                acc2[i] = fmaf(x4.z, w4.z, acc2[i]);
                acc2[i] = fmaf(x4.w, w4.w, acc2[i]);
            }
        }
        float* osc = out + OUT_MV_ELEMS;
        float bo = b2_s[s];
        #pragma unroll
        for (int i = 0; i < 4; ++i) {
            int t = t0 + th * 4 + i;
            __builtin_nontemporal_store(acc2[i] + bo, &osc[(size_t)t * SSC + s]);
        }
    }
}

// ---------------------------------------------------------------------------
// Fallback (ws too small): f32 mv gather + W_eff via LDS stage (unchanged).
// ---------------------------------------------------------------------------
__global__ __launch_bounds__(256) void kBf_mv(
        const float* __restrict__ mv_src,
        const float* __restrict__ mv_skip,
        const float* __restrict__ pos_src,
        const float* __restrict__ pos_tgt,
        const int*   __restrict__ isrc,
        const float* __restrict__ W1_mv,
        const float* __restrict__ W2_mv,
        float* __restrict__ out) {
    __shared__ float sWeff[CMV + CSKIP][MVD];
    __shared__ float stage[4][256];
    int tid = threadIdx.x;
    for (int e = tid; e < (CMV + CSKIP) * MVD; e += 256) {
        int c = e >> 4, d = e & 15;
        float a = 0.f;
        #pragma unroll 8
        for (int h = 0; h < HID; ++h)
            a = fmaf(W1_mv[c * HID + h], W2_mv[h * MVD + d], a);
        sWeff[c][d] = a;
    }
    __syncthreads();

    int lane = tid & 63, wv = tid >> 6;
    int d = lane >> 2, q = lane & 3;
    float wcol[CMV + CSKIP];
    #pragma unroll
    for (int c = 0; c < CMV + CSKIP; ++c) wcol[c] = sWeff[c][d];

    int wid = (int)((blockIdx.x * blockDim.x + tid) >> 6);
    int nw  = (int)((gridDim.x * blockDim.x) >> 6);
    for (int t = wid; t < N_TGT; t += nw) {
        float w = 0.f; int src = 0;
        if (lane < KNN) {
            src = isrc[t * KNN + lane];
            float dx = pos_src[src * 3 + 0] - pos_tgt[t * 3 + 0];
            float dy = pos_src[src * 3 + 1] - pos_tgt[t * 3 + 1];
            float dz = pos_src[src * 3 + 2] - pos_tgt[t * 3 + 2];
            float d2 = fmaxf(dx * dx + dy * dy + dz * dz, 1e-16f);
            w = 1.0f / d2;
        }
        float denom = w;
        denom += __shfl_xor(denom, 1);
        denom += __shfl_xor(denom, 2);
        denom += __shfl_xor(denom, 4);
        denom = __shfl(denom, 0);
        float invd = 1.0f / denom;

        float4 acc = make_float4(0.f, 0.f, 0.f, 0.f);
        #pragma unroll
        for (int k = 0; k < KNN; ++k) {
            int   sk = __builtin_amdgcn_readlane(src, k);
            float wk = __uint_as_float(__builtin_amdgcn_readlane(__float_as_uint(w), k));
            float4 v = *(const float4*)(mv_src + (size_t)sk * 256 + lane * 4);
            acc.x = fmaf(wk, v.x, acc.x);
            acc.y = fmaf(wk, v.y, acc.y);
            acc.z = fmaf(wk, v.z, acc.z);
            acc.w = fmaf(wk, v.w, acc.w);
        }
        asm volatile("" ::: "memory");
        *(float4*)&stage[wv][lane * 4] = acc;
        asm volatile("s_waitcnt lgkmcnt(0)" ::: "memory");
        __builtin_amdgcn_sched_barrier(0);

        float4 o = make_float4(0.f, 0.f, 0.f, 0.f);
        #pragma unroll
        for (int c = 0; c < CMV; ++c) {
            float4 v = *(const float4*)&stage[wv][c * 16 + q * 4];
            o.x = fmaf(v.x, wcol[c], o.x);
            o.y = fmaf(v.y, wcol[c], o.y);
            o.z = fmaf(v.z, wcol[c], o.z);
            o.w = fmaf(v.w, wcol[c], o.w);
        }
        const float4 u0 = *(const float4*)(mv_skip + (size_t)t * 32 + q * 4);
        const float4 u1 = *(const float4*)(mv_skip + (size_t)t * 32 + 16 + q * 4);
        float4 r;
        r.x = fmaf(o.x, invd, fmaf(wcol[16], u0.x, wcol[17] * u1.x));
        r.y = fmaf(o.y, invd, fmaf(wcol[16], u0.y, wcol[17] * u1.y));
        r.z = fmaf(o.z, invd, fmaf(wcol[16], u0.z, wcol[17] * u1.z));
        r.w = fmaf(o.w, invd, fmaf(wcol[16], u0.w, wcol[17] * u1.w));
        *(float4*)(out + (size_t)t * 256 + lane * 4) = r;
    }
}

// ---------------------------------------------------------------------------
// Fallback scalar path (pos recompute; used only when ws is too small).
// ---------------------------------------------------------------------------
__global__ __launch_bounds__(256) void kC_scalar(
        const float* __restrict__ sc_src,
        const float* __restrict__ sc_skip,
        const float* __restrict__ pos_src,
        const float* __restrict__ pos_tgt,
        const int*   __restrict__ isrc,
        const float* __restrict__ W1_s,
        const float* __restrict__ b1_s,
        const float* __restrict__ W2_s,
        const float* __restrict__ b2_s,
        float* __restrict__ out) {
    __shared__ float sW1[HID * HID];
    __shared__ float sW2T[SSC][68];
    __shared__ float sXT[HID][68];
    __shared__ float sH[64][68];
    __shared__ float swgt[64][9];
    __shared__ int   ssrcl[64][9];
    __shared__ float sb1[HID], sb2[SSC];

    int tid = threadIdx.x;
    #pragma unroll
    for (int r = 0; r < 4; ++r) {
        float4 v = *(const float4*)(W1_s + (r * 256 + tid) * 4);
        *(float4*)&sW1[(r * 256 + tid) * 4] = v;
    }
    for (int e = tid; e < HID * SSC; e += 256) {
        int h = e >> 5, s = e & 31;
        sW2T[s][h] = W2_s[e];
    }
    if (tid < HID) sb1[tid] = b1_s[tid];
    else if (tid < HID + SSC) sb2[tid - HID] = b2_s[tid - HID];

    int t0 = blockIdx.x * 64;
    if (tid < 64) {
        int t = t0 + tid;
        int4 e0 = *(const int4*)(isrc + t * KNN);
        int4 e1 = *(const int4*)(isrc + t * KNN + 4);
        int sk[KNN] = {e0.x, e0.y, e0.z, e0.w, e1.x, e1.y, e1.z, e1.w};
        float wkn[KNN];
        float ptx = pos_tgt[t * 3 + 0], pty = pos_tgt[t * 3 + 1], ptz = pos_tgt[t * 3 + 2];
        float den = 0.f;
        #pragma unroll
        for (int k = 0; k < KNN; ++k) {
            int s = sk[k];
            float dx = pos_src[s * 3 + 0] - ptx;
            float dy = pos_src[s * 3 + 1] - pty;
            float dz = pos_src[s * 3 + 2] - ptz;
            float d2 = fmaxf(dx * dx + dy * dy + dz * dz, 1e-16f);
            wkn[k] = 1.0f / d2;
            den += wkn[k];
        }
        float invd = 1.0f / den;
        #pragma unroll
        for (int k = 0; k < KNN; ++k) {
            swgt[tid][k]  = wkn[k] * invd;
            ssrcl[tid][k] = sk[k];
        }
    }
    __syncthreads();

    {
        int wv = tid >> 6, lane = tid & 63;
        int k = lane >> 3;
        int m = lane & 7;
        for (int i = 0; i < 16; i += 4) {
            int tb = wv * 16 + i;
            float4 v[4]; float wn4[4];
            #pragma unroll
            for (int j = 0; j < 4; ++j) {
                int tl = tb + j;
                wn4[j] = swgt[tl][k];
                int sk = ssrcl[tl][k];
                v[j] = *(const float4*)(sc_src + (size_t)sk * SSC + m * 4);
            }
            float4 u;
            if (lane < 32)
                u = *(const float4*)(sc_skip + (size_t)(t0 + tb + k) * SSC + m * 4);
            #pragma unroll
            for (int j = 0; j < 4; ++j) {
                float4 a = v[j]; float wnj = wn4[j];
                a.x *= wnj; a.y *= wnj; a.z *= wnj; a.w *= wnj;
                #pragma unroll
                for (int sft = 8; sft <= 32; sft <<= 1) {
                    a.x += __shfl_xor(a.x, sft);
                    a.y += __shfl_xor(a.y, sft);
                    a.z += __shfl_xor(a.z, sft);
                    a.w += __shfl_xor(a.w, sft);
                }
                if (lane < 8) {
                    sXT[4 * lane + 0][tb + j] = a.x;
                    sXT[4 * lane + 1][tb + j] = a.y;
                    sXT[4 * lane + 2][tb + j] = a.z;
                    sXT[4 * lane + 3][tb + j] = a.w;
                }
            }
            if (lane < 32) {
                sXT[SSC + 4 * m + 0][tb + k] = u.x;
                sXT[SSC + 4 * m + 1][tb + k] = u.y;
                sXT[SSC + 4 * m + 2][tb + k] = u.z;
                sXT[SSC + 4 * m + 3][tb + k] = u.w;
            }
        }
    }
    __syncthreads();

    int wv = tid >> 6;
    int lane = tid & 63;
    int tr4 = lane >> 4;
    int hc  = lane & 15;
    int tbase = wv * 16 + tr4 * 4;
    float acc[4][4];
    #pragma unroll
    for (int i = 0; i < 4; ++i)
        #pragma unroll
        for (int j = 0; j < 4; ++j) acc[i][j] = 0.f;

    #pragma unroll 2
    for (int c = 0; c < HID; ++c) {
        float4 xv = *(const float4*)&sXT[c][tbase];
        float4 wv4 = *(const float4*)&sW1[c * HID + hc * 4];
        acc[0][0] = fmaf(xv.x, wv4.x, acc[0][0]);
        acc[0][1] = fmaf(xv.x, wv4.y, acc[0][1]);
        acc[0][2] = fmaf(xv.x, wv4.z, acc[0][2]);
        acc[0][3] = fmaf(xv.x, wv4.w, acc[0][3]);
        acc[1][0] = fmaf(xv.y, wv4.x, acc[1][0]);
        acc[1][1] = fmaf(xv.y, wv4.y, acc[1][1]);
        acc[1][2] = fmaf(xv.y, wv4.z, acc[1][2]);
        acc[1][3] = fmaf(xv.y, wv4.w, acc[1][3]);
        acc[2][0] = fmaf(xv.z, wv4.x, acc[2][0]);
        acc[2][1] = fmaf(xv.z, wv4.y, acc[2][1]);
        acc[2][2] = fmaf(xv.z, wv4.z, acc[2][2]);
        acc[2][3] = fmaf(xv.z, wv4.w, acc[2][3]);
        acc[3][0] = fmaf(xv.w, wv4.x, acc[3][0]);
        acc[3][1] = fmaf(xv.w, wv4.y, acc[3][1]);
        acc[3][2] = fmaf(xv.w, wv4.z, acc[3][2]);
        acc[3][3] = fmaf(xv.w, wv4.w, acc[3][3]);
    }
    {
        float b0 = sb1[hc * 4 + 0], b1 = sb1[hc * 4 + 1];
        float b2 = sb1[hc * 4 + 2], b3 = sb1[hc * 4 + 3];
        #pragma unroll
        for (int i = 0; i < 4; ++i) {
            float4 hv;
            hv.x = gelu_tanh(acc[i][0] + b0);
            hv.y = gelu_tanh(acc[i][1] + b1);
            hv.z = gelu_tanh(acc[i][2] + b2);
            hv.w = gelu_tanh(acc[i][3] + b3);
            *(float4*)&sH[tbase + i][hc * 4] = hv;
        }
    }
    __syncthreads();

    int sc16 = lane & 15;
    float acc2[4][2];
    #pragma unroll
    for (int i = 0; i < 4; ++i) { acc2[i][0] = 0.f; acc2[i][1] = 0.f; }
    #pragma unroll 2
    for (int hh = 0; hh < 16; ++hh) {
        float4 wa = *(const float4*)&sW2T[sc16 * 2 + 0][hh * 4];
        float4 wb = *(const float4*)&sW2T[sc16 * 2 + 1][hh * 4];
        #pragma unroll
        for (int i = 0; i < 4; ++i) {
            float4 hv = *(const float4*)&sH[tbase + i][hh * 4];
            acc2[i][0] = fmaf(hv.x, wa.x, acc2[i][0]);
            acc2[i][0] = fmaf(hv.y, wa.y, acc2[i][0]);
            acc2[i][0] = fmaf(hv.z, wa.z, acc2[i][0]);
            acc2[i][0] = fmaf(hv.w, wa.w, acc2[i][0]);
            acc2[i][1] = fmaf(hv.x, wb.x, acc2[i][1]);
            acc2[i][1] = fmaf(hv.y, wb.y, acc2[i][1]);
            acc2[i][1] = fmaf(hv.z, wb.z, acc2[i][1]);
            acc2[i][1] = fmaf(hv.w, wb.w, acc2[i][1]);
        }
    }
    float* osc = out + OUT_MV_ELEMS;
    float bb0 = sb2[sc16 * 2 + 0], bb1 = sb2[sc16 * 2 + 1];
    #pragma unroll
    for (int i = 0; i < 4; ++i) {
        int t = t0 + tbase + i;
        float2 r = make_float2(acc2[i][0] + bb0, acc2[i][1] + bb1);
        *(float2*)&osc[(size_t)t * SSC + sc16 * 2] = r;
    }
}

// ---------------------------------------------------------------------------
extern "C" void kernel_launch(void* const* d_in, const int* in_sizes, int n_in,
                              void* d_out, int out_size, void* d_ws, size_t ws_size,
                              hipStream_t stream) {
    const float* mv_src   = (const float*)d_in[0];
    const float* mv_skip  = (const float*)d_in[1];
    const float* sc_src   = (const float*)d_in[2];
    const float* sc_skip  = (const float*)d_in[3];
    const float* pos_src  = (const float*)d_in[4];
    const float* pos_tgt  = (const float*)d_in[5];
    const int*   isrc     = (const int*)d_in[6];
    // d_in[7] = interp_target: structurally repeat(arange(N_TGT), K) -- unused
    const float* W1_mv    = (const float*)d_in[8];
    const float* W2_mv    = (const float*)d_in[9];
    const float* W1_s     = (const float*)d_in[10];
    const float* b1_s     = (const float*)d_in[11];
    const float* W2_s     = (const float*)d_in[12];
    const float* b2_s     = (const float*)d_in[13];
    float* out = (float*)d_out;
    float* ws  = (float*)d_ws;

    size_t need_ws_bytes = (size_t)(WN_OFFSET + (size_t)N_TGT * KNN) * sizeof(float);
    if (ws_size >= need_ws_bytes) {
        hipLaunchKernelGGL(kA_preproject, dim3(512), dim3(256), 0, stream,
                           mv_src, pos_src, pos_tgt, isrc, W1_mv, W2_mv, ws);
        hipLaunchKernelGGL(kFused, dim3(10240), dim3(256), 0, stream,
                           ws, mv_skip, sc_src, sc_skip, isrc,
                           W1_s, b1_s, W2_s, b2_s, out);
    } else {
        hipLaunchKernelGGL(kBf_mv, dim3(2048), dim3(256), 0, stream,
                           mv_src, mv_skip, pos_src, pos_tgt, isrc, W1_mv, W2_mv, out);
        hipLaunchKernelGGL(kC_scalar, dim3(N_TGT / 64), dim3(256), 0, stream,
                           sc_src, sc_skip, pos_src, pos_tgt, isrc,
                           W1_s, b1_s, W2_s, b2_s, out);
    }
}